// Round 6
// baseline (1368.553 us; speedup 1.0000x reference)
//
#include <hip/hip_runtime.h>
#include <cstdint>
#include <cstddef>

// Bidirectional 3-layer tanh RNN, S=512 B=512 D=300 H=256.
// R5b: chunk-pipelined layers (slot s: layer l on chunk s-l), launch-boundary sync.
//     gemm0: 64-row tiles, 2-3 blocks/CU, x read once, bias0 folded.
//     pipe: z as MFMA C-init, emit in next step's MFMA shadow, hoisted ds_reads,
//     split chains for L2, cvt_pkrtz packing, lgkmcnt-only barrier.
//     (R5 compile fix: cvt_pkrtz returns __fp16 ext_vector(2))

#define SEQ   512
#define BATCH 512
#define DIN   300
#define HDIM  256
#define NT    512
#define CH    64
#define NCH   (SEQ / CH)    // 8
#define NSLOT (NCH + 2)     // 10

typedef _Float16 f16x8 __attribute__((ext_vector_type(8)));
typedef __fp16   fp16x2 __attribute__((ext_vector_type(2)));
typedef float    f32x4 __attribute__((ext_vector_type(4)));

// ---- ws layout ----
#define WIH0_E 0            // f16 [2 dir][16ct][10kt][64][8]
#define WHH_E  163840       // f16 [2][3 layer][16ct][8kt][64][8]
#define WIHN_E 557056       // f16 [2][2 (->l1,l2)][16ct][8kt][64][8]
#define HC_BYTE 1638400     // u16 [2 dir][3 layer][512][256]
#define Z_BYTE  3211264     // 3 z buffers, each u16 [2 dir][512 t][ZTILE]
#define ZTILE  131072       // u16 per (d,t) tile, fragment-major
#define ZBUF_E 134217728ull

#define KEEP(x) asm volatile("" : "+v"(x))

static __device__ __forceinline__ uint16_t f16bits(_Float16 h) {
    union { _Float16 h; uint16_t u; } v; v.h = h; return v.u;
}
static __device__ __forceinline__ uint32_t pk2(float a, float b) {
    union { fp16x2 h; uint32_t u; } v; v.h = __builtin_amdgcn_cvt_pkrtz(a, b); return v.u;
}

// ---------------- prep: weights -> f16 fragment layout ----------------
__global__ void rnn_prep(const float* __restrict__ fW_ih0, const float* __restrict__ fW_ih,
                         const float* __restrict__ fW_hh,  const float* __restrict__ bW_ih0,
                         const float* __restrict__ bW_ih,  const float* __restrict__ bW_hh,
                         _Float16* __restrict__ wf)
{
    const int gid = blockIdx.x * 256 + threadIdx.x;   // 0..102399
    const int d = gid / 51200;
    const int r = gid - d * 51200;
    const int lane = r & 63;
    const float* Wih0 = d ? bW_ih0 : fW_ih0;
    const float* Wih  = d ? bW_ih  : fW_ih;
    const float* Whh  = d ? bW_hh  : fW_hh;
    _Float16 vals[8];
    size_t dstE;
    if (r < 10240) {                       // W_ih0 frags, K=320 padded
        const int ck = r >> 6, ct = ck / 10, kt = ck - ct * 10;
        const int col = ct * 16 + (lane & 15);
        const int k0  = kt * 32 + (lane >> 4) * 8;
        #pragma unroll
        for (int e = 0; e < 8; ++e) {
            const int k = k0 + e;
            vals[e] = (k < 300) ? (_Float16)Wih0[(size_t)k * 256 + col] : (_Float16)0.f;
        }
        dstE = (size_t)WIH0_E + (size_t)d * 81920 + (size_t)r * 8;
    } else if (r < 34816) {                // W_hh frags
        const int rr = r - 10240, l = rr / 8192, r2 = rr - l * 8192;
        const int ck = r2 >> 6, ct = ck >> 3, kt = ck & 7;
        const int col = ct * 16 + (lane & 15);
        const int k0  = kt * 32 + (lane >> 4) * 8;
        #pragma unroll
        for (int e = 0; e < 8; ++e)
            vals[e] = (_Float16)Whh[((size_t)(l * 256 + k0 + e)) * 256 + col];
        dstE = (size_t)WHH_E + (size_t)(d * 3 + l) * 65536 + (size_t)r2 * 8;
    } else {                               // W_ih layers 1,2 frags
        const int rr = r - 34816, ln = rr / 8192, r2 = rr - ln * 8192;
        const int ck = r2 >> 6, ct = ck >> 3, kt = ck & 7;
        const int col = ct * 16 + (lane & 15);
        const int k0  = kt * 32 + (lane >> 4) * 8;
        #pragma unroll
        for (int e = 0; e < 8; ++e)
            vals[e] = (_Float16)Wih[((size_t)(ln * 256 + k0 + e)) * 256 + col];
        dstE = (size_t)WIHN_E + (size_t)(d * 2 + ln) * 65536 + (size_t)r2 * 8;
    }
    *(f16x8*)(wf + dstE) = *(const f16x8*)vals;
}

// ---------------- gemm0: Zin0 = x @ W_ih0 + b0, both dirs per block ----------------
__global__ __launch_bounds__(NT, 4) void rnn_gemm0(const float* __restrict__ x,
                                                   const _Float16* __restrict__ wih0,
                                                   const float* __restrict__ fb,
                                                   const float* __restrict__ bb,
                                                   uint16_t* __restrict__ z0)
{
    __shared__ uint16_t Xl[64 * 328];      // 64 rows x K=320 (+8 pad), f16 -> 42 KB
    const int tid = threadIdx.x, lane = tid & 63, w = tid >> 6;
    const int colw = lane & 15, rq = lane >> 4, rq8 = rq * 8;
    const int ct0 = w * 2;
    const int s = blockIdx.x >> 3, rb = blockIdx.x & 7;   // 512 s x 8 row-tiles
    const int b0 = rb * 64;

    for (int p = tid; p < 9600; p += NT) {             // stage 64 rows of x (read once)
        const int r = p / 150, c2 = (p - r * 150) * 2;
        const float2 v = *(const float2*)(x + (size_t)(s * BATCH + b0 + r) * DIN + c2);
        *(uint32_t*)&Xl[r * 328 + c2] = pk2(v.x, v.y);
    }
    for (int p = tid; p < 640; p += NT) {              // zero pad k in [300,320)
        const int r = p / 10, c2 = 300 + (p - r * 10) * 2;
        *(uint32_t*)&Xl[r * 328 + c2] = 0;
    }
    __syncthreads();

    #pragma unroll 1
    for (int dd = 0; dd < 2; ++dd) {                   // dirs sequential, reuse regs
        const _Float16* W = wih0 + (size_t)dd * 81920;
        const float* bias = dd ? bb : fb;              // layer-0 bias folded here
        const float bv0 = bias[ct0 * 16 + colw];
        const float bv1 = bias[(ct0 + 1) * 16 + colw];
        const int t = dd ? (SEQ - 1 - s) : s;
        f16x8 wv[2][10];
        #pragma unroll
        for (int c = 0; c < 2; ++c)
            #pragma unroll
            for (int kt = 0; kt < 10; ++kt)
                wv[c][kt] = *(const f16x8*)(W + (((size_t)(ct0 + c) * 10 + kt) * 64 + lane) * 8);
        f32x4 acc[4][2] = {};
        #pragma unroll
        for (int kt = 0; kt < 10; ++kt)
            #pragma unroll
            for (int m = 0; m < 4; ++m) {
                const f16x8 a = *(const f16x8*)&Xl[(m * 16 + (lane & 15)) * 328 + kt * 32 + rq8];
                acc[m][0] = __builtin_amdgcn_mfma_f32_16x16x32_f16(a, wv[0][kt], acc[m][0], 0, 0, 0);
                acc[m][1] = __builtin_amdgcn_mfma_f32_16x16x32_f16(a, wv[1][kt], acc[m][1], 0, 0, 0);
            }
        uint16_t* zt = z0 + (size_t)(dd * SEQ + t) * ZTILE;
        #pragma unroll
        for (int m = 0; m < 4; ++m)
            #pragma unroll
            for (int c = 0; c < 2; ++c) {
                const float bc = c ? bv1 : bv0;
                uint2 sv;
                sv.x = pk2(acc[m][c][0] + bc, acc[m][c][1] + bc);
                sv.y = pk2(acc[m][c][2] + bc, acc[m][c][3] + bc);
                const int T = rb * 4 + m;
                *(uint2*)(zt + (((T * 16 + ct0 + c) * 4 + rq) * 64 + colw * 4)) = sv;
            }
    }
}

// ---------------- pipelined recurrent kernel ----------------
template<int L>
__device__ __forceinline__ void pipe_run(const _Float16* whh_all, const _Float16* wihn_all,
                                         const uint16_t* zsrc, uint16_t* zdst,
                                         uint16_t* hcarry, const float* fb, const float* bb,
                                         float* out, int d, int i, int cs, uint16_t* Hb)
{
    const int tid = threadIdx.x, lane = tid & 63, w = tid >> 6;
    const int colw = lane & 15, rq = lane >> 4, rq8 = rq * 8;
    const int ct0 = w * 2;
    const int grow0 = i * 16;
    const int tbase = cs * CH;

    // ---- weights -> pinned registers ----
    const _Float16* whh = whh_all + (size_t)(d * 3 + L) * 65536;
    f16x8 wh0[8], wh1[8];
    #pragma unroll
    for (int kt = 0; kt < 8; ++kt) {
        wh0[kt] = *(const f16x8*)(whh + (((size_t)ct0 * 8 + kt) * 64 + lane) * 8);
        wh1[kt] = *(const f16x8*)(whh + (((size_t)(ct0 + 1) * 8 + kt) * 64 + lane) * 8);
    }
    #pragma unroll
    for (int kt = 0; kt < 8; ++kt) { KEEP(wh0[kt]); KEEP(wh1[kt]); }
    f16x8 wn0[8], wn1[8];
    float bn0 = 0.f, bn1 = 0.f;
    if constexpr (L < 2) {
        const _Float16* wnx = wihn_all + (size_t)(d * 2 + L) * 65536;
        #pragma unroll
        for (int kt = 0; kt < 8; ++kt) {
            wn0[kt] = *(const f16x8*)(wnx + (((size_t)ct0 * 8 + kt) * 64 + lane) * 8);
            wn1[kt] = *(const f16x8*)(wnx + (((size_t)(ct0 + 1) * 8 + kt) * 64 + lane) * 8);
        }
        #pragma unroll
        for (int kt = 0; kt < 8; ++kt) { KEEP(wn0[kt]); KEEP(wn1[kt]); }
        const float* bnx = (d ? bb : fb) + (L + 1) * HDIM;   // next-layer bias, folded at emit
        bn0 = bnx[ct0 * 16 + colw];
        bn1 = bnx[(ct0 + 1) * 16 + colw];
    }

    // ---- init h LDS (zero; carry-in to buffer 1) ----
    for (int p = tid; p < 4224; p += NT) ((uint32_t*)Hb)[p] = 0;
    __syncthreads();
    if (cs > 0) {
        const uint16_t* hc = hcarry + (size_t)(d * 3 + L) * 131072;
        const int row = tid >> 5, c8 = (tid & 31) * 8;
        *(uint4*)&Hb[4224 + row * 264 + c8] = *(const uint4*)(hc + (size_t)(grow0 + row) * 256 + c8);
    }
    __syncthreads();

    // ---- z addressing (fragment-major) ----
    const uint16_t* zsb = zsrc + (size_t)(d * SEQ + tbase) * ZTILE;
    uint16_t* zdb = nullptr;
    if constexpr (L < 2) zdb = zdst + (size_t)(d * SEQ + tbase) * ZTILE;
    const int off0 = ((i * 16 + ct0) * 4 + rq) * 64 + colw * 4;
    const int off1 = ((i * 16 + ct0 + 1) * 4 + rq) * 64 + colw * 4;

    uint2 zc0 = *(const uint2*)(zsb + off0);
    uint2 zc1 = *(const uint2*)(zsb + off1);
    uint2 za0 = *(const uint2*)(zsb + ZTILE + off0);
    uint2 za1 = *(const uint2*)(zsb + ZTILE + off1);

    f32x4 anp0 = {}, anp1 = {};                        // an of previous step (emit-delayed)

    #pragma unroll 1
    for (int k = 0; k < CH; ++k) {
        const int cur = k & 1, prv = cur ^ 1;          // tbase even -> parity = k&1

        // prefetch z for step k+2 (in flight across barrier; no vmcnt drain)
        const int kp = (k + 2 < CH) ? (k + 2) : (CH - 1);
        const uint2 zb0v = *(const uint2*)(zsb + (size_t)kp * ZTILE + off0);
        const uint2 zb1v = *(const uint2*)(zsb + (size_t)kp * ZTILE + off1);

        // hoisted fragment reads: one latency, pipelined
        f16x8 ah[8];
        #pragma unroll
        for (int kt = 0; kt < 8; ++kt)
            ah[kt] = *(const f16x8*)&Hb[prv * 4224 + (lane & 15) * 264 + kt * 32 + rq8];

        // C-init = z(t) (bias already folded by producer)
        f32x4 ar0, ar1;
        {
            union { uint2 u; _Float16 h[4]; } a, b;
            a.u = zc0; b.u = zc1;
            ar0 = (f32x4){(float)a.h[0], (float)a.h[1], (float)a.h[2], (float)a.h[3]};
            ar1 = (f32x4){(float)b.h[0], (float)b.h[1], (float)b.h[2], (float)b.h[3]};
        }

        f32x4 an0, an1;
        if constexpr (L < 2) {
            an0 = (f32x4){bn0, bn0, bn0, bn0};         // next-layer bias as C-init
            an1 = (f32x4){bn1, bn1, bn1, bn1};
            #pragma unroll
            for (int kt = 0; kt < 8; ++kt) {           // 4 chains, dep distance 4
                ar0 = __builtin_amdgcn_mfma_f32_16x16x32_f16(ah[kt], wh0[kt], ar0, 0, 0, 0);
                ar1 = __builtin_amdgcn_mfma_f32_16x16x32_f16(ah[kt], wh1[kt], ar1, 0, 0, 0);
                an0 = __builtin_amdgcn_mfma_f32_16x16x32_f16(ah[kt], wn0[kt], an0, 0, 0, 0);
                an1 = __builtin_amdgcn_mfma_f32_16x16x32_f16(ah[kt], wn1[kt], an1, 0, 0, 0);
            }
        } else {
            f32x4 arB0 = {}, arB1 = {};                // split chains: dep distance 4
            #pragma unroll
            for (int kt = 0; kt < 4; ++kt) {
                ar0  = __builtin_amdgcn_mfma_f32_16x16x32_f16(ah[kt],     wh0[kt],     ar0,  0, 0, 0);
                ar1  = __builtin_amdgcn_mfma_f32_16x16x32_f16(ah[kt],     wh1[kt],     ar1,  0, 0, 0);
                arB0 = __builtin_amdgcn_mfma_f32_16x16x32_f16(ah[4 + kt], wh0[4 + kt], arB0, 0, 0, 0);
                arB1 = __builtin_amdgcn_mfma_f32_16x16x32_f16(ah[4 + kt], wh1[4 + kt], arB1, 0, 0, 0);
            }
            ar0 = ar0 + arB0;
            ar1 = ar1 + arB1;
        }

        // emit z_next(t-2) in the MFMA shadow (values from previous iteration)
        if constexpr (L < 2) {
            if (k >= 2) {
                uint2 s0, s1;
                s0.x = pk2(anp0[0], anp0[1]); s0.y = pk2(anp0[2], anp0[3]);
                s1.x = pk2(anp1[0], anp1[1]); s1.y = pk2(anp1[2], anp1[3]);
                *(uint2*)(zdb + (size_t)(k - 2) * ZTILE + off0) = s0;
                *(uint2*)(zdb + (size_t)(k - 2) * ZTILE + off1) = s1;
            }
        }

        // activation: h = tanh(S), S already = z + b + h@Whh
        #pragma unroll
        for (int q = 0; q < 8; ++q) {
            const float S = (q < 4) ? ar0[q] : ar1[q - 4];
            const float e = __builtin_amdgcn_exp2f(S * 2.885390081777927f);
            const float r = __builtin_amdgcn_rcpf(e + 1.f);
            const float hv = __builtin_fmaf(-2.f, r, 1.f);
            const int c = q >> 2, j = q & 3;
            Hb[cur * 4224 + (rq * 4 + j) * 264 + (ct0 + c) * 16 + colw] = f16bits((_Float16)hv);
            if (L == 2 && tbase + k == SEQ - 1)
                out[(size_t)(grow0 + rq * 4 + j) * 512 + d * 256 + (ct0 + c) * 16 + colw] = hv;
        }

        if constexpr (L < 2) { anp0 = an0; anp1 = an1; }
        zc0 = za0; zc1 = za1; za0 = zb0v; za1 = zb1v;

        // barrier WITHOUT vmcnt drain: only LDS ops must settle
        __builtin_amdgcn_sched_barrier(0);
        asm volatile("s_waitcnt lgkmcnt(0)" ::: "memory");
        __builtin_amdgcn_s_barrier();
        __builtin_amdgcn_sched_barrier(0);
    }

    if constexpr (L < 2) {
        // emit slot CH-2 (from last loop iteration's an)
        {
            uint2 s0, s1;
            s0.x = pk2(anp0[0], anp0[1]); s0.y = pk2(anp0[2], anp0[3]);
            s1.x = pk2(anp1[0], anp1[1]); s1.y = pk2(anp1[2], anp1[3]);
            *(uint2*)(zdb + (size_t)(CH - 2) * ZTILE + off0) = s0;
            *(uint2*)(zdb + (size_t)(CH - 2) * ZTILE + off1) = s1;
        }
        // tail GEMM for slot CH-1 from final h (buffer 1)
        f32x4 an0 = (f32x4){bn0, bn0, bn0, bn0};
        f32x4 an1 = (f32x4){bn1, bn1, bn1, bn1};
        #pragma unroll
        for (int kt = 0; kt < 8; ++kt) {
            const f16x8 ah = *(const f16x8*)&Hb[4224 + (lane & 15) * 264 + kt * 32 + rq8];
            an0 = __builtin_amdgcn_mfma_f32_16x16x32_f16(ah, wn0[kt], an0, 0, 0, 0);
            an1 = __builtin_amdgcn_mfma_f32_16x16x32_f16(ah, wn1[kt], an1, 0, 0, 0);
        }
        uint2 s0, s1;
        s0.x = pk2(an0[0], an0[1]); s0.y = pk2(an0[2], an0[3]);
        s1.x = pk2(an1[0], an1[1]); s1.y = pk2(an1[2], an1[3]);
        *(uint2*)(zdb + (size_t)(CH - 1) * ZTILE + off0) = s0;
        *(uint2*)(zdb + (size_t)(CH - 1) * ZTILE + off1) = s1;
    }
    // h carry out (final h in buffer 1; CH even)
    {
        uint16_t* hc = hcarry + (size_t)(d * 3 + L) * 131072;
        const int row = tid >> 5, c8 = (tid & 31) * 8;
        *(uint4*)(hc + (size_t)(grow0 + row) * 256 + c8) = *(const uint4*)&Hb[4224 + row * 264 + c8];
    }
}

__global__ __launch_bounds__(NT, 2) void rnn_pipe(const _Float16* whh_all,
                                                  const _Float16* wihn_all,
                                                  uint16_t* z0, uint16_t* z1, uint16_t* z2,
                                                  uint16_t* hcarry,
                                                  const float* fb, const float* bb,
                                                  float* out, int slot)
{
    __shared__ uint16_t Hb[2 * 16 * 264];
    const int l = blockIdx.x >> 6, sub = blockIdx.x & 63;
    const int d = sub >> 5, i = sub & 31;
    const int cs = slot - l;
    if (cs < 0 || cs >= NCH) return;
    if (l == 0)      pipe_run<0>(whh_all, wihn_all, z0, z1, hcarry, fb, bb, out, d, i, cs, Hb);
    else if (l == 1) pipe_run<1>(whh_all, wihn_all, z1, z2, hcarry, fb, bb, out, d, i, cs, Hb);
    else             pipe_run<2>(whh_all, wihn_all, z2, nullptr, hcarry, fb, bb, out, d, i, cs, Hb);
}

extern "C" void kernel_launch(void* const* d_in, const int* in_sizes, int n_in,
                              void* d_out, int out_size, void* d_ws, size_t ws_size,
                              hipStream_t stream)
{
    (void)in_sizes; (void)n_in; (void)out_size; (void)ws_size;
    const float* x      = (const float*)d_in[0];
    const float* fW_ih0 = (const float*)d_in[1];
    const float* fW_ih  = (const float*)d_in[2];
    const float* fW_hh  = (const float*)d_in[3];
    const float* fb     = (const float*)d_in[4];
    const float* bW_ih0 = (const float*)d_in[5];
    const float* bW_ih  = (const float*)d_in[6];
    const float* bW_hh  = (const float*)d_in[7];
    const float* bb     = (const float*)d_in[8];
    uint8_t* ws = (uint8_t*)d_ws;

    _Float16* wf     = (_Float16*)ws;
    uint16_t* hcarry = (uint16_t*)(ws + HC_BYTE);
    uint16_t* z0     = (uint16_t*)(ws + Z_BYTE);
    uint16_t* z1     = z0 + ZBUF_E;
    uint16_t* z2     = z1 + ZBUF_E;
    const _Float16* whh  = wf + WHH_E;
    const _Float16* wihn = wf + WIHN_E;
    float* out = (float*)d_out;

    rnn_prep<<<400, 256, 0, stream>>>(fW_ih0, fW_ih, fW_hh, bW_ih0, bW_ih, bW_hh, wf);
    rnn_gemm0<<<4096, NT, 0, stream>>>(x, wf, fb, bb, z0);
    for (int s = 0; s < NSLOT; ++s)
        rnn_pipe<<<192, NT, 0, stream>>>(whh, wihn, z0, z1, z2, hcarry, fb, bb, out, s);
}

// Round 7
// 1192.160 us; speedup vs baseline: 1.1480x; 1.1480x over previous
//
#include <hip/hip_runtime.h>
#include <cstdint>
#include <cstddef>

// Bidirectional 3-layer tanh RNN, S=512 B=512 D=300 H=256.
// R7: gemm0 rebuilt with s-loop weight reuse (TS=16, dbuf LDS, 256 blocks,
//     16B paired stores, bias as MFMA C-init). Pipe keeps 8-wave R5 structure
//     + 16B paired emit stores + 3-step z prefetch depth.

#define SEQ   512
#define BATCH 512
#define DIN   300
#define HDIM  256
#define NT    512
#define CH    64
#define NCH   (SEQ / CH)    // 8
#define NSLOT (NCH + 2)     // 10
#define TS    16            // timesteps per gemm0 block

typedef _Float16 f16x8 __attribute__((ext_vector_type(8)));
typedef __fp16   fp16x2 __attribute__((ext_vector_type(2)));
typedef float    f32x4 __attribute__((ext_vector_type(4)));

// ---- ws layout ----
#define WIH0_E 0            // f16 [2 dir][16ct][10kt][64][8]
#define WHH_E  163840       // f16 [2][3 layer][16ct][8kt][64][8]
#define WIHN_E 557056       // f16 [2][2 (->l1,l2)][16ct][8kt][64][8]
#define HC_BYTE 1638400     // u16 [2 dir][3 layer][512][256]
#define Z_BYTE  3211264     // 3 z buffers, each u16 [2 dir][512 t][ZTILE]
#define ZTILE  131072       // u16 per (d,t) tile, fragment-major
#define ZBUF_E 134217728ull

#define KEEP(x) asm volatile("" : "+v"(x))

static __device__ __forceinline__ uint16_t f16bits(_Float16 h) {
    union { _Float16 h; uint16_t u; } v; v.h = h; return v.u;
}
static __device__ __forceinline__ uint32_t pk2(float a, float b) {
    union { fp16x2 h; uint32_t u; } v; v.h = __builtin_amdgcn_cvt_pkrtz(a, b); return v.u;
}

// paired 16B store: even lane stores its own 8B + odd neighbor's 8B
static __device__ __forceinline__ void pair_store(uint16_t* addr, int lane, uint32_t x, uint32_t y) {
    const uint32_t ox = (uint32_t)__shfl_xor((int)x, 1);
    const uint32_t oy = (uint32_t)__shfl_xor((int)y, 1);
    if (!(lane & 1)) *(uint4*)addr = make_uint4(x, y, ox, oy);
}

// ---------------- prep: weights -> f16 fragment layout ----------------
__global__ void rnn_prep(const float* __restrict__ fW_ih0, const float* __restrict__ fW_ih,
                         const float* __restrict__ fW_hh,  const float* __restrict__ bW_ih0,
                         const float* __restrict__ bW_ih,  const float* __restrict__ bW_hh,
                         _Float16* __restrict__ wf)
{
    const int gid = blockIdx.x * 256 + threadIdx.x;   // 0..102399
    const int d = gid / 51200;
    const int r = gid - d * 51200;
    const int lane = r & 63;
    const float* Wih0 = d ? bW_ih0 : fW_ih0;
    const float* Wih  = d ? bW_ih  : fW_ih;
    const float* Whh  = d ? bW_hh  : fW_hh;
    _Float16 vals[8];
    size_t dstE;
    if (r < 10240) {                       // W_ih0 frags, K=320 padded
        const int ck = r >> 6, ct = ck / 10, kt = ck - ct * 10;
        const int col = ct * 16 + (lane & 15);
        const int k0  = kt * 32 + (lane >> 4) * 8;
        #pragma unroll
        for (int e = 0; e < 8; ++e) {
            const int k = k0 + e;
            vals[e] = (k < 300) ? (_Float16)Wih0[(size_t)k * 256 + col] : (_Float16)0.f;
        }
        dstE = (size_t)WIH0_E + (size_t)d * 81920 + (size_t)r * 8;
    } else if (r < 34816) {                // W_hh frags
        const int rr = r - 10240, l = rr / 8192, r2 = rr - l * 8192;
        const int ck = r2 >> 6, ct = ck >> 3, kt = ck & 7;
        const int col = ct * 16 + (lane & 15);
        const int k0  = kt * 32 + (lane >> 4) * 8;
        #pragma unroll
        for (int e = 0; e < 8; ++e)
            vals[e] = (_Float16)Whh[((size_t)(l * 256 + k0 + e)) * 256 + col];
        dstE = (size_t)WHH_E + (size_t)(d * 3 + l) * 65536 + (size_t)r2 * 8;
    } else {                               // W_ih layers 1,2 frags
        const int rr = r - 34816, ln = rr / 8192, r2 = rr - ln * 8192;
        const int ck = r2 >> 6, ct = ck >> 3, kt = ck & 7;
        const int col = ct * 16 + (lane & 15);
        const int k0  = kt * 32 + (lane >> 4) * 8;
        #pragma unroll
        for (int e = 0; e < 8; ++e)
            vals[e] = (_Float16)Wih[((size_t)(ln * 256 + k0 + e)) * 256 + col];
        dstE = (size_t)WIHN_E + (size_t)(d * 2 + ln) * 65536 + (size_t)r2 * 8;
    }
    *(f16x8*)(wf + dstE) = *(const f16x8*)vals;
}

// ---------------- gemm0: Zin0 = x @ W_ih0 + b0 ----------------
// 256 blocks = 32 s-groups x 8 row-tiles(64). Each block: TS=16 timesteps,
// weights in registers the whole time, double-buffered x staging.
__global__ __launch_bounds__(NT, 1) void rnn_gemm0(const float* __restrict__ x,
                                                   const _Float16* __restrict__ wih0,
                                                   const float* __restrict__ fb,
                                                   const float* __restrict__ bb,
                                                   uint16_t* __restrict__ z0)
{
    __shared__ uint16_t Xl[2][64 * 332];   // 2 x 42.5 KB
    const int tid = threadIdx.x, lane = tid & 63, w = tid >> 6;
    const int colw = lane & 15, rq = lane >> 4, rq8 = rq * 8;
    const int ct0 = w * 2;
    const int sg = blockIdx.x >> 3, rb = blockIdx.x & 7;
    const int b0 = rb * 64;

    // weights for both dirs, pinned
    f16x8 wv[2][2][10];
    #pragma unroll
    for (int dd = 0; dd < 2; ++dd)
        #pragma unroll
        for (int c = 0; c < 2; ++c)
            #pragma unroll
            for (int kt = 0; kt < 10; ++kt)
                wv[dd][c][kt] = *(const f16x8*)(wih0 + (size_t)dd * 81920
                                                + (((size_t)(ct0 + c) * 10 + kt) * 64 + lane) * 8);
    #pragma unroll
    for (int dd = 0; dd < 2; ++dd)
        #pragma unroll
        for (int c = 0; c < 2; ++c)
            #pragma unroll
            for (int kt = 0; kt < 10; ++kt) KEEP(wv[dd][c][kt]);

    float bv[2][2];
    #pragma unroll
    for (int dd = 0; dd < 2; ++dd)
        #pragma unroll
        for (int c = 0; c < 2; ++c)
            bv[dd][c] = (dd ? bb : fb)[(ct0 + c) * 16 + colw];

    // zero pad region k in [300,320) of both buffers
    for (int p = tid; p < 640; p += NT) {
        const int r = p / 10, q = p - r * 10;
        *(uint32_t*)&Xl[0][r * 332 + 300 + q * 2] = 0;
        *(uint32_t*)&Xl[1][r * 332 + 300 + q * 2] = 0;
    }
    // stage si=0
    {
        const float* xs = x + ((size_t)(sg * TS) * BATCH + b0) * DIN;
        for (int p = tid; p < 9600; p += NT) {
            const int r = p / 150, c2 = (p - r * 150) * 2;
            const float2 v = *(const float2*)(xs + (size_t)r * DIN + c2);
            *(uint32_t*)&Xl[0][r * 332 + c2] = pk2(v.x, v.y);
        }
    }
    __syncthreads();

    #pragma unroll 1
    for (int si = 0; si < TS; ++si) {
        const int s = sg * TS + si;
        const int buf = si & 1;

        #pragma unroll 1
        for (int dd = 0; dd < 2; ++dd) {
            f32x4 acc[4][2];
            #pragma unroll
            for (int m = 0; m < 4; ++m)
                #pragma unroll
                for (int c = 0; c < 2; ++c)
                    acc[m][c] = (f32x4){bv[dd][c], bv[dd][c], bv[dd][c], bv[dd][c]};
            #pragma unroll
            for (int kt = 0; kt < 10; ++kt)
                #pragma unroll
                for (int m = 0; m < 4; ++m) {
                    const f16x8 a = *(const f16x8*)&Xl[buf][(m * 16 + colw) * 332 + kt * 32 + rq8];
                    acc[m][0] = __builtin_amdgcn_mfma_f32_16x16x32_f16(a, wv[dd][0][kt], acc[m][0], 0, 0, 0);
                    acc[m][1] = __builtin_amdgcn_mfma_f32_16x16x32_f16(a, wv[dd][1][kt], acc[m][1], 0, 0, 0);
                }
            const int t = dd ? (SEQ - 1 - s) : s;
            uint16_t* zt = z0 + (size_t)(dd * SEQ + t) * ZTILE;
            #pragma unroll
            for (int m = 0; m < 4; ++m)
                #pragma unroll
                for (int c = 0; c < 2; ++c) {
                    const uint32_t sx = pk2(acc[m][c][0], acc[m][c][1]);
                    const uint32_t sy = pk2(acc[m][c][2], acc[m][c][3]);
                    pair_store(zt + ((size_t)((rb * 4 + m) * 16 + ct0 + c) * 4 + rq) * 64 + colw * 4,
                               lane, sx, sy);
                }
        }

        // stage si+1 into other buffer
        if (si < TS - 1) {
            const float* xs = x + ((size_t)(sg * TS + si + 1) * BATCH + b0) * DIN;
            #pragma unroll
            for (int b = 0; b < 19; ++b) {
                const int p = tid + b * NT;
                if (p < 9600) {
                    const int r = p / 150, c2 = (p - r * 150) * 2;
                    const float2 v = *(const float2*)(xs + (size_t)r * DIN + c2);
                    *(uint32_t*)&Xl[buf ^ 1][r * 332 + c2] = pk2(v.x, v.y);
                }
            }
        }
        // lgkm-only barrier: z stores stay in flight
        __builtin_amdgcn_sched_barrier(0);
        asm volatile("s_waitcnt lgkmcnt(0)" ::: "memory");
        __builtin_amdgcn_s_barrier();
        __builtin_amdgcn_sched_barrier(0);
    }
}

// ---------------- pipelined recurrent kernel ----------------
template<int L>
__device__ __forceinline__ void pipe_run(const _Float16* whh_all, const _Float16* wihn_all,
                                         const uint16_t* zsrc, uint16_t* zdst,
                                         uint16_t* hcarry, const float* fb, const float* bb,
                                         float* out, int d, int i, int cs, uint16_t* Hb)
{
    const int tid = threadIdx.x, lane = tid & 63, w = tid >> 6;
    const int colw = lane & 15, rq = lane >> 4, rq8 = rq * 8;
    const int ct0 = w * 2;
    const int grow0 = i * 16;
    const int tbase = cs * CH;

    // ---- weights -> pinned registers ----
    const _Float16* whh = whh_all + (size_t)(d * 3 + L) * 65536;
    f16x8 wh0[8], wh1[8];
    #pragma unroll
    for (int kt = 0; kt < 8; ++kt) {
        wh0[kt] = *(const f16x8*)(whh + (((size_t)ct0 * 8 + kt) * 64 + lane) * 8);
        wh1[kt] = *(const f16x8*)(whh + (((size_t)(ct0 + 1) * 8 + kt) * 64 + lane) * 8);
    }
    #pragma unroll
    for (int kt = 0; kt < 8; ++kt) { KEEP(wh0[kt]); KEEP(wh1[kt]); }
    f16x8 wn0[8], wn1[8];
    float bn0 = 0.f, bn1 = 0.f;
    if constexpr (L < 2) {
        const _Float16* wnx = wihn_all + (size_t)(d * 2 + L) * 65536;
        #pragma unroll
        for (int kt = 0; kt < 8; ++kt) {
            wn0[kt] = *(const f16x8*)(wnx + (((size_t)ct0 * 8 + kt) * 64 + lane) * 8);
            wn1[kt] = *(const f16x8*)(wnx + (((size_t)(ct0 + 1) * 8 + kt) * 64 + lane) * 8);
        }
        #pragma unroll
        for (int kt = 0; kt < 8; ++kt) { KEEP(wn0[kt]); KEEP(wn1[kt]); }
        const float* bnx = (d ? bb : fb) + (L + 1) * HDIM;
        bn0 = bnx[ct0 * 16 + colw];
        bn1 = bnx[(ct0 + 1) * 16 + colw];
    }

    // ---- init h LDS (zero; carry-in to buffer 1) ----
    for (int p = tid; p < 4224; p += NT) ((uint32_t*)Hb)[p] = 0;
    __syncthreads();
    if (cs > 0) {
        const uint16_t* hc = hcarry + (size_t)(d * 3 + L) * 131072;
        const int row = tid >> 5, c8 = (tid & 31) * 8;
        *(uint4*)&Hb[4224 + row * 264 + c8] = *(const uint4*)(hc + (size_t)(grow0 + row) * 256 + c8);
    }
    __syncthreads();

    // ---- z addressing (fragment-major) ----
    const uint16_t* zsb = zsrc + (size_t)(d * SEQ + tbase) * ZTILE;
    uint16_t* zdb = nullptr;
    if constexpr (L < 2) zdb = zdst + (size_t)(d * SEQ + tbase) * ZTILE;
    const int off0 = ((i * 16 + ct0) * 4 + rq) * 64 + colw * 4;
    const int off1 = ((i * 16 + ct0 + 1) * 4 + rq) * 64 + colw * 4;

    // 3-deep z prefetch pipeline: zc (k), za (k+1), zb (k+2)
    uint2 zc0 = *(const uint2*)(zsb + off0);
    uint2 zc1 = *(const uint2*)(zsb + off1);
    uint2 za0 = *(const uint2*)(zsb + ZTILE + off0);
    uint2 za1 = *(const uint2*)(zsb + ZTILE + off1);
    uint2 zb0 = *(const uint2*)(zsb + 2 * ZTILE + off0);
    uint2 zb1 = *(const uint2*)(zsb + 2 * ZTILE + off1);

    f32x4 anp0 = {}, anp1 = {};                        // an of previous step (emit-delayed)

    #pragma unroll 1
    for (int k = 0; k < CH; ++k) {
        const int cur = k & 1, prv = cur ^ 1;

        // prefetch z for step k+3
        const int kp = (k + 3 < CH) ? (k + 3) : (CH - 1);
        const uint2 zd0 = *(const uint2*)(zsb + (size_t)kp * ZTILE + off0);
        const uint2 zd1 = *(const uint2*)(zsb + (size_t)kp * ZTILE + off1);

        // hoisted fragment reads
        f16x8 ah[8];
        #pragma unroll
        for (int kt = 0; kt < 8; ++kt)
            ah[kt] = *(const f16x8*)&Hb[prv * 4224 + (lane & 15) * 264 + kt * 32 + rq8];

        // C-init = z(t)
        f32x4 ar0, ar1;
        {
            union { uint2 u; _Float16 h[4]; } a, b;
            a.u = zc0; b.u = zc1;
            ar0 = (f32x4){(float)a.h[0], (float)a.h[1], (float)a.h[2], (float)a.h[3]};
            ar1 = (f32x4){(float)b.h[0], (float)b.h[1], (float)b.h[2], (float)b.h[3]};
        }

        f32x4 an0, an1;
        if constexpr (L < 2) {
            an0 = (f32x4){bn0, bn0, bn0, bn0};
            an1 = (f32x4){bn1, bn1, bn1, bn1};
            #pragma unroll
            for (int kt = 0; kt < 8; ++kt) {
                ar0 = __builtin_amdgcn_mfma_f32_16x16x32_f16(ah[kt], wh0[kt], ar0, 0, 0, 0);
                ar1 = __builtin_amdgcn_mfma_f32_16x16x32_f16(ah[kt], wh1[kt], ar1, 0, 0, 0);
                an0 = __builtin_amdgcn_mfma_f32_16x16x32_f16(ah[kt], wn0[kt], an0, 0, 0, 0);
                an1 = __builtin_amdgcn_mfma_f32_16x16x32_f16(ah[kt], wn1[kt], an1, 0, 0, 0);
            }
        } else {
            f32x4 arB0 = {}, arB1 = {};
            #pragma unroll
            for (int kt = 0; kt < 4; ++kt) {
                ar0  = __builtin_amdgcn_mfma_f32_16x16x32_f16(ah[kt],     wh0[kt],     ar0,  0, 0, 0);
                ar1  = __builtin_amdgcn_mfma_f32_16x16x32_f16(ah[kt],     wh1[kt],     ar1,  0, 0, 0);
                arB0 = __builtin_amdgcn_mfma_f32_16x16x32_f16(ah[4 + kt], wh0[4 + kt], arB0, 0, 0, 0);
                arB1 = __builtin_amdgcn_mfma_f32_16x16x32_f16(ah[4 + kt], wh1[4 + kt], arB1, 0, 0, 0);
            }
            ar0 = ar0 + arB0;
            ar1 = ar1 + arB1;
        }

        // emit z_next(t-2) in the MFMA shadow (paired 16B stores)
        if constexpr (L < 2) {
            if (k >= 2) {
                pair_store(zdb + (size_t)(k - 2) * ZTILE + off0, lane,
                           pk2(anp0[0], anp0[1]), pk2(anp0[2], anp0[3]));
                pair_store(zdb + (size_t)(k - 2) * ZTILE + off1, lane,
                           pk2(anp1[0], anp1[1]), pk2(anp1[2], anp1[3]));
            }
        }

        // activation
        #pragma unroll
        for (int q = 0; q < 8; ++q) {
            const float S = (q < 4) ? ar0[q] : ar1[q - 4];
            const float e = __builtin_amdgcn_exp2f(S * 2.885390081777927f);
            const float r = __builtin_amdgcn_rcpf(e + 1.f);
            const float hv = __builtin_fmaf(-2.f, r, 1.f);
            const int c = q >> 2, j = q & 3;
            Hb[cur * 4224 + (rq * 4 + j) * 264 + (ct0 + c) * 16 + colw] = f16bits((_Float16)hv);
            if (L == 2 && tbase + k == SEQ - 1)
                out[(size_t)(grow0 + rq * 4 + j) * 512 + d * 256 + (ct0 + c) * 16 + colw] = hv;
        }

        if constexpr (L < 2) { anp0 = an0; anp1 = an1; }
        zc0 = za0; zc1 = za1; za0 = zb0; za1 = zb1; zb0 = zd0; zb1 = zd1;

        __builtin_amdgcn_sched_barrier(0);
        asm volatile("s_waitcnt lgkmcnt(0)" ::: "memory");
        __builtin_amdgcn_s_barrier();
        __builtin_amdgcn_sched_barrier(0);
    }

    if constexpr (L < 2) {
        // emit slot CH-2 (from last iteration's an)
        pair_store(zdb + (size_t)(CH - 2) * ZTILE + off0, lane,
                   pk2(anp0[0], anp0[1]), pk2(anp0[2], anp0[3]));
        pair_store(zdb + (size_t)(CH - 2) * ZTILE + off1, lane,
                   pk2(anp1[0], anp1[1]), pk2(anp1[2], anp1[3]));
        // tail GEMM for slot CH-1 from final h (buffer 1)
        f32x4 an0 = (f32x4){bn0, bn0, bn0, bn0};
        f32x4 an1 = (f32x4){bn1, bn1, bn1, bn1};
        #pragma unroll
        for (int kt = 0; kt < 8; ++kt) {
            const f16x8 ah = *(const f16x8*)&Hb[4224 + (lane & 15) * 264 + kt * 32 + rq8];
            an0 = __builtin_amdgcn_mfma_f32_16x16x32_f16(ah, wn0[kt], an0, 0, 0, 0);
            an1 = __builtin_amdgcn_mfma_f32_16x16x32_f16(ah, wn1[kt], an1, 0, 0, 0);
        }
        pair_store(zdb + (size_t)(CH - 1) * ZTILE + off0, lane,
                   pk2(an0[0], an0[1]), pk2(an0[2], an0[3]));
        pair_store(zdb + (size_t)(CH - 1) * ZTILE + off1, lane,
                   pk2(an1[0], an1[1]), pk2(an1[2], an1[3]));
    }
    // h carry out (final h in buffer 1; CH even)
    {
        uint16_t* hc = hcarry + (size_t)(d * 3 + L) * 131072;
        const int row = tid >> 5, c8 = (tid & 31) * 8;
        *(uint4*)(hc + (size_t)(grow0 + row) * 256 + c8) = *(const uint4*)&Hb[4224 + row * 264 + c8];
    }
}

__global__ __launch_bounds__(NT, 2) void rnn_pipe(const _Float16* whh_all,
                                                  const _Float16* wihn_all,
                                                  uint16_t* z0, uint16_t* z1, uint16_t* z2,
                                                  uint16_t* hcarry,
                                                  const float* fb, const float* bb,
                                                  float* out, int slot)
{
    __shared__ uint16_t Hb[2 * 16 * 264];
    const int l = blockIdx.x >> 6, sub = blockIdx.x & 63;
    const int d = sub >> 5, i = sub & 31;
    const int cs = slot - l;
    if (cs < 0 || cs >= NCH) return;
    if (l == 0)      pipe_run<0>(whh_all, wihn_all, z0, z1, hcarry, fb, bb, out, d, i, cs, Hb);
    else if (l == 1) pipe_run<1>(whh_all, wihn_all, z1, z2, hcarry, fb, bb, out, d, i, cs, Hb);
    else             pipe_run<2>(whh_all, wihn_all, z2, nullptr, hcarry, fb, bb, out, d, i, cs, Hb);
}

extern "C" void kernel_launch(void* const* d_in, const int* in_sizes, int n_in,
                              void* d_out, int out_size, void* d_ws, size_t ws_size,
                              hipStream_t stream)
{
    (void)in_sizes; (void)n_in; (void)out_size; (void)ws_size;
    const float* x      = (const float*)d_in[0];
    const float* fW_ih0 = (const float*)d_in[1];
    const float* fW_ih  = (const float*)d_in[2];
    const float* fW_hh  = (const float*)d_in[3];
    const float* fb     = (const float*)d_in[4];
    const float* bW_ih0 = (const float*)d_in[5];
    const float* bW_ih  = (const float*)d_in[6];
    const float* bW_hh  = (const float*)d_in[7];
    const float* bb     = (const float*)d_in[8];
    uint8_t* ws = (uint8_t*)d_ws;

    _Float16* wf     = (_Float16*)ws;
    uint16_t* hcarry = (uint16_t*)(ws + HC_BYTE);
    uint16_t* z0     = (uint16_t*)(ws + Z_BYTE);
    uint16_t* z1     = z0 + ZBUF_E;
    uint16_t* z2     = z1 + ZBUF_E;
    const _Float16* whh  = wf + WHH_E;
    const _Float16* wihn = wf + WIHN_E;
    float* out = (float*)d_out;

    rnn_prep<<<400, 256, 0, stream>>>(fW_ih0, fW_ih, fW_hh, bW_ih0, bW_ih, bW_hh, wf);
    rnn_gemm0<<<256, NT, 0, stream>>>(x, wf, fb, bb, z0);
    for (int s = 0; s < NSLOT; ++s)
        rnn_pipe<<<192, NT, 0, stream>>>(whh, wihn, z0, z1, z2, hcarry, fb, bb, out, s);
}

// Round 8
// 1092.703 us; speedup vs baseline: 1.2524x; 1.0910x over previous
//
#include <hip/hip_runtime.h>
#include <cstdint>
#include <cstddef>

// Bidirectional 3-layer tanh RNN, S=512 B=512 D=300 H=256.
// R8: z buffers re-laid out so each lane stores/loads one contiguous 16B chunk
//     (wave = 1KB contiguous -> no partial-granule RMW at TCC).
//     amdgpu_waves_per_eu(2,2) forces 256-VGPR budget (kill spills).
//     gemm0: one dir per block (512 blocks), dir pairs share x via same-XCD L2,
//     TS=16 weight reuse, m-split accumulators (fits 128 VGPR regardless).

#define SEQ   512
#define BATCH 512
#define DIN   300
#define HDIM  256
#define NT    512
#define CH    64
#define NCH   (SEQ / CH)    // 8
#define NSLOT (NCH + 2)     // 10
#define TS    16            // timesteps per gemm0 block

typedef _Float16 f16x8 __attribute__((ext_vector_type(8)));
typedef __fp16   fp16x2 __attribute__((ext_vector_type(2)));
typedef float    f32x4 __attribute__((ext_vector_type(4)));

// ---- ws layout ----
#define WIH0_E 0            // f16 [2 dir][16ct][10kt][64][8]
#define WHH_E  163840       // f16 [2][3 layer][16ct][8kt][64][8]
#define WIHN_E 557056       // f16 [2][2 (->l1,l2)][16ct][8kt][64][8]
#define HC_BYTE 1638400     // u16 [2 dir][3 layer][512][256]
#define Z_BYTE  3211264     // 3 z buffers, each u16 [2 dir][512 t][ZTILE]
#define ZTILE  131072       // u16 per (d,t) tile
#define ZBUF_E 134217728ull

// z tile layout: lane-chunked fragment-major.
// offset(i, w, lane, c, j) = ((i*8 + w)*64 + lane)*8 + c*4 + j   (u16 units)
// -> each lane owns 16B contiguous; each wave owns 1KB contiguous.

#define KEEP(x) asm volatile("" : "+v"(x))

static __device__ __forceinline__ uint16_t f16bits(_Float16 h) {
    union { _Float16 h; uint16_t u; } v; v.h = h; return v.u;
}
static __device__ __forceinline__ uint32_t pk2(float a, float b) {
    union { fp16x2 h; uint32_t u; } v; v.h = __builtin_amdgcn_cvt_pkrtz(a, b); return v.u;
}

// ---------------- prep: weights -> f16 fragment layout ----------------
__global__ void rnn_prep(const float* __restrict__ fW_ih0, const float* __restrict__ fW_ih,
                         const float* __restrict__ fW_hh,  const float* __restrict__ bW_ih0,
                         const float* __restrict__ bW_ih,  const float* __restrict__ bW_hh,
                         _Float16* __restrict__ wf)
{
    const int gid = blockIdx.x * 256 + threadIdx.x;   // 0..102399
    const int d = gid / 51200;
    const int r = gid - d * 51200;
    const int lane = r & 63;
    const float* Wih0 = d ? bW_ih0 : fW_ih0;
    const float* Wih  = d ? bW_ih  : fW_ih;
    const float* Whh  = d ? bW_hh  : fW_hh;
    _Float16 vals[8];
    size_t dstE;
    if (r < 10240) {                       // W_ih0 frags, K=320 padded
        const int ck = r >> 6, ct = ck / 10, kt = ck - ct * 10;
        const int col = ct * 16 + (lane & 15);
        const int k0  = kt * 32 + (lane >> 4) * 8;
        #pragma unroll
        for (int e = 0; e < 8; ++e) {
            const int k = k0 + e;
            vals[e] = (k < 300) ? (_Float16)Wih0[(size_t)k * 256 + col] : (_Float16)0.f;
        }
        dstE = (size_t)WIH0_E + (size_t)d * 81920 + (size_t)r * 8;
    } else if (r < 34816) {                // W_hh frags
        const int rr = r - 10240, l = rr / 8192, r2 = rr - l * 8192;
        const int ck = r2 >> 6, ct = ck >> 3, kt = ck & 7;
        const int col = ct * 16 + (lane & 15);
        const int k0  = kt * 32 + (lane >> 4) * 8;
        #pragma unroll
        for (int e = 0; e < 8; ++e)
            vals[e] = (_Float16)Whh[((size_t)(l * 256 + k0 + e)) * 256 + col];
        dstE = (size_t)WHH_E + (size_t)(d * 3 + l) * 65536 + (size_t)r2 * 8;
    } else {                               // W_ih layers 1,2 frags
        const int rr = r - 34816, ln = rr / 8192, r2 = rr - ln * 8192;
        const int ck = r2 >> 6, ct = ck >> 3, kt = ck & 7;
        const int col = ct * 16 + (lane & 15);
        const int k0  = kt * 32 + (lane >> 4) * 8;
        #pragma unroll
        for (int e = 0; e < 8; ++e)
            vals[e] = (_Float16)Wih[((size_t)(ln * 256 + k0 + e)) * 256 + col];
        dstE = (size_t)WIHN_E + (size_t)(d * 2 + ln) * 65536 + (size_t)r2 * 8;
    }
    *(f16x8*)(wf + dstE) = *(const f16x8*)vals;
}

// ---------------- gemm0: Zin0 = x @ W_ih0 + b0 ----------------
// 512 blocks: sg = bid>>4 (0..31), dd = (bid>>3)&1, rb = bid&7.
// dir pair (bid, bid^8) reads the same x slice on the same XCD -> L2 reuse.
// TS=16 timesteps per block; weights (one dir, 80 VGPR) held in registers.
__global__ __attribute__((amdgpu_flat_work_group_size(NT, NT), amdgpu_waves_per_eu(2, 2)))
void rnn_gemm0(const float* __restrict__ x,
               const _Float16* __restrict__ wih0,
               const float* __restrict__ fb,
               const float* __restrict__ bb,
               uint16_t* __restrict__ z0)
{
    __shared__ uint16_t Xl[2][64 * 332];   // 2 x 42.5 KB
    const int tid = threadIdx.x, lane = tid & 63, w = tid >> 6;
    const int colw = lane & 15, rq = lane >> 4, rq8 = rq * 8;
    const int ct0 = w * 2;
    const int sg = blockIdx.x >> 4, dd = (blockIdx.x >> 3) & 1, rb = blockIdx.x & 7;
    const int b0 = rb * 64;

    // weights for this dir, pinned (20 frags = 80 VGPR)
    f16x8 wv[2][10];
    #pragma unroll
    for (int c = 0; c < 2; ++c)
        #pragma unroll
        for (int kt = 0; kt < 10; ++kt)
            wv[c][kt] = *(const f16x8*)(wih0 + (size_t)dd * 81920
                                        + (((size_t)(ct0 + c) * 10 + kt) * 64 + lane) * 8);
    #pragma unroll
    for (int c = 0; c < 2; ++c)
        #pragma unroll
        for (int kt = 0; kt < 10; ++kt) KEEP(wv[c][kt]);

    float bv[2];
    #pragma unroll
    for (int c = 0; c < 2; ++c) bv[c] = (dd ? bb : fb)[(ct0 + c) * 16 + colw];

    // zero pad region k in [300,320) of both buffers
    for (int p = tid; p < 640; p += NT) {
        const int r = p / 10, q = p - r * 10;
        *(uint32_t*)&Xl[0][r * 332 + 300 + q * 2] = 0;
        *(uint32_t*)&Xl[1][r * 332 + 300 + q * 2] = 0;
    }
    // stage si=0
    {
        const float* xs = x + ((size_t)(sg * TS) * BATCH + b0) * DIN;
        for (int p = tid; p < 9600; p += NT) {
            const int r = p / 150, c2 = (p - r * 150) * 2;
            const float2 v = *(const float2*)(xs + (size_t)r * DIN + c2);
            *(uint32_t*)&Xl[0][r * 332 + c2] = pk2(v.x, v.y);
        }
    }
    __syncthreads();

    #pragma unroll 1
    for (int si = 0; si < TS; ++si) {
        const int s = sg * TS + si;
        const int buf = si & 1;
        const int t = dd ? (SEQ - 1 - s) : s;
        uint16_t* zt = z0 + (size_t)(dd * SEQ + t) * ZTILE;

        #pragma unroll 1
        for (int half = 0; half < 2; ++half) {         // m-split: acc fits 16 VGPR
            f32x4 acc[2][2];
            #pragma unroll
            for (int m = 0; m < 2; ++m)
                #pragma unroll
                for (int c = 0; c < 2; ++c)
                    acc[m][c] = (f32x4){bv[c], bv[c], bv[c], bv[c]};
            #pragma unroll
            for (int kt = 0; kt < 10; ++kt)
                #pragma unroll
                for (int m = 0; m < 2; ++m) {
                    const int mrow = half * 2 + m;
                    const f16x8 a = *(const f16x8*)&Xl[buf][(mrow * 16 + colw) * 332 + kt * 32 + rq8];
                    acc[m][0] = __builtin_amdgcn_mfma_f32_16x16x32_f16(a, wv[0][kt], acc[m][0], 0, 0, 0);
                    acc[m][1] = __builtin_amdgcn_mfma_f32_16x16x32_f16(a, wv[1][kt], acc[m][1], 0, 0, 0);
                }
            #pragma unroll
            for (int m = 0; m < 2; ++m) {
                const int i = rb * 4 + half * 2 + m;
                uint4 sv;
                sv.x = pk2(acc[m][0][0], acc[m][0][1]);
                sv.y = pk2(acc[m][0][2], acc[m][0][3]);
                sv.z = pk2(acc[m][1][0], acc[m][1][1]);
                sv.w = pk2(acc[m][1][2], acc[m][1][3]);
                *(uint4*)(zt + ((size_t)(i * 8 + w) * 64 + lane) * 8) = sv;
            }
        }

        // stage si+1 into other buffer
        if (si < TS - 1) {
            const float* xs = x + ((size_t)(sg * TS + si + 1) * BATCH + b0) * DIN;
            for (int p = tid; p < 9600; p += NT) {
                const int r = p / 150, c2 = (p - r * 150) * 2;
                const float2 v = *(const float2*)(xs + (size_t)r * DIN + c2);
                *(uint32_t*)&Xl[buf ^ 1][r * 332 + c2] = pk2(v.x, v.y);
            }
        }
        // lgkm-only barrier: z stores stay in flight
        __builtin_amdgcn_sched_barrier(0);
        asm volatile("s_waitcnt lgkmcnt(0)" ::: "memory");
        __builtin_amdgcn_s_barrier();
        __builtin_amdgcn_sched_barrier(0);
    }
}

// ---------------- pipelined recurrent kernel ----------------
template<int L>
__device__ __forceinline__ void pipe_run(const _Float16* whh_all, const _Float16* wihn_all,
                                         const uint16_t* zsrc, uint16_t* zdst,
                                         uint16_t* hcarry, const float* fb, const float* bb,
                                         float* out, int d, int i, int cs, uint16_t* Hb)
{
    const int tid = threadIdx.x, lane = tid & 63, w = tid >> 6;
    const int colw = lane & 15, rq = lane >> 4, rq8 = rq * 8;
    const int ct0 = w * 2;
    const int grow0 = i * 16;
    const int tbase = cs * CH;

    // ---- weights -> pinned registers ----
    const _Float16* whh = whh_all + (size_t)(d * 3 + L) * 65536;
    f16x8 wh0[8], wh1[8];
    #pragma unroll
    for (int kt = 0; kt < 8; ++kt) {
        wh0[kt] = *(const f16x8*)(whh + (((size_t)ct0 * 8 + kt) * 64 + lane) * 8);
        wh1[kt] = *(const f16x8*)(whh + (((size_t)(ct0 + 1) * 8 + kt) * 64 + lane) * 8);
    }
    #pragma unroll
    for (int kt = 0; kt < 8; ++kt) { KEEP(wh0[kt]); KEEP(wh1[kt]); }
    f16x8 wn0[8], wn1[8];
    float bn0 = 0.f, bn1 = 0.f;
    if constexpr (L < 2) {
        const _Float16* wnx = wihn_all + (size_t)(d * 2 + L) * 65536;
        #pragma unroll
        for (int kt = 0; kt < 8; ++kt) {
            wn0[kt] = *(const f16x8*)(wnx + (((size_t)ct0 * 8 + kt) * 64 + lane) * 8);
            wn1[kt] = *(const f16x8*)(wnx + (((size_t)(ct0 + 1) * 8 + kt) * 64 + lane) * 8);
        }
        #pragma unroll
        for (int kt = 0; kt < 8; ++kt) { KEEP(wn0[kt]); KEEP(wn1[kt]); }
        const float* bnx = (d ? bb : fb) + (L + 1) * HDIM;
        bn0 = bnx[ct0 * 16 + colw];
        bn1 = bnx[(ct0 + 1) * 16 + colw];
    }

    // ---- init h LDS (zero; carry-in to buffer 1) ----
    for (int p = tid; p < 4224; p += NT) ((uint32_t*)Hb)[p] = 0;
    __syncthreads();
    if (cs > 0) {
        const uint16_t* hc = hcarry + (size_t)(d * 3 + L) * 131072;
        const int row = tid >> 5, c8 = (tid & 31) * 8;
        *(uint4*)&Hb[4224 + row * 264 + c8] = *(const uint4*)(hc + (size_t)(grow0 + row) * 256 + c8);
    }
    __syncthreads();

    // ---- z addressing (lane-chunked layout) ----
    const uint16_t* zsb = zsrc + (size_t)(d * SEQ + tbase) * ZTILE;
    uint16_t* zdb = nullptr;
    if constexpr (L < 2) zdb = zdst + (size_t)(d * SEQ + tbase) * ZTILE;
    const size_t zoff = ((size_t)(i * 8 + w) * 64 + lane) * 8;

    // 3-deep z prefetch pipeline
    uint4 zc = *(const uint4*)(zsb + zoff);
    uint4 za = *(const uint4*)(zsb + ZTILE + zoff);
    uint4 zb = *(const uint4*)(zsb + 2 * ZTILE + zoff);

    f32x4 anp0 = {}, anp1 = {};                        // an of previous step (emit-delayed)

    #pragma unroll 1
    for (int k = 0; k < CH; ++k) {
        const int cur = k & 1, prv = cur ^ 1;

        // prefetch z for step k+3
        const int kp = (k + 3 < CH) ? (k + 3) : (CH - 1);
        const uint4 zd = *(const uint4*)(zsb + (size_t)kp * ZTILE + zoff);

        // hoisted fragment reads
        f16x8 ah[8];
        #pragma unroll
        for (int kt = 0; kt < 8; ++kt)
            ah[kt] = *(const f16x8*)&Hb[prv * 4224 + colw * 264 + kt * 32 + rq8];

        // C-init = z(t)
        f32x4 ar0, ar1;
        {
            union { uint4 u; _Float16 h[8]; } zz; zz.u = zc;
            ar0 = (f32x4){(float)zz.h[0], (float)zz.h[1], (float)zz.h[2], (float)zz.h[3]};
            ar1 = (f32x4){(float)zz.h[4], (float)zz.h[5], (float)zz.h[6], (float)zz.h[7]};
        }

        f32x4 an0, an1;
        if constexpr (L < 2) {
            an0 = (f32x4){bn0, bn0, bn0, bn0};
            an1 = (f32x4){bn1, bn1, bn1, bn1};
            #pragma unroll
            for (int kt = 0; kt < 8; ++kt) {
                ar0 = __builtin_amdgcn_mfma_f32_16x16x32_f16(ah[kt], wh0[kt], ar0, 0, 0, 0);
                ar1 = __builtin_amdgcn_mfma_f32_16x16x32_f16(ah[kt], wh1[kt], ar1, 0, 0, 0);
                an0 = __builtin_amdgcn_mfma_f32_16x16x32_f16(ah[kt], wn0[kt], an0, 0, 0, 0);
                an1 = __builtin_amdgcn_mfma_f32_16x16x32_f16(ah[kt], wn1[kt], an1, 0, 0, 0);
            }
        } else {
            f32x4 arB0 = {}, arB1 = {};
            #pragma unroll
            for (int kt = 0; kt < 4; ++kt) {
                ar0  = __builtin_amdgcn_mfma_f32_16x16x32_f16(ah[kt],     wh0[kt],     ar0,  0, 0, 0);
                ar1  = __builtin_amdgcn_mfma_f32_16x16x32_f16(ah[kt],     wh1[kt],     ar1,  0, 0, 0);
                arB0 = __builtin_amdgcn_mfma_f32_16x16x32_f16(ah[4 + kt], wh0[4 + kt], arB0, 0, 0, 0);
                arB1 = __builtin_amdgcn_mfma_f32_16x16x32_f16(ah[4 + kt], wh1[4 + kt], arB1, 0, 0, 0);
            }
            ar0 = ar0 + arB0;
            ar1 = ar1 + arB1;
        }

        // emit z_next(t-2) in the MFMA shadow (full 16B lane store)
        if constexpr (L < 2) {
            if (k >= 2) {
                uint4 sv;
                sv.x = pk2(anp0[0], anp0[1]); sv.y = pk2(anp0[2], anp0[3]);
                sv.z = pk2(anp1[0], anp1[1]); sv.w = pk2(anp1[2], anp1[3]);
                *(uint4*)(zdb + (size_t)(k - 2) * ZTILE + zoff) = sv;
            }
        }

        // activation
        #pragma unroll
        for (int q = 0; q < 8; ++q) {
            const float S = (q < 4) ? ar0[q] : ar1[q - 4];
            const float e = __builtin_amdgcn_exp2f(S * 2.885390081777927f);
            const float r = __builtin_amdgcn_rcpf(e + 1.f);
            const float hv = __builtin_fmaf(-2.f, r, 1.f);
            const int c = q >> 2, j = q & 3;
            Hb[cur * 4224 + (rq * 4 + j) * 264 + (ct0 + c) * 16 + colw] = f16bits((_Float16)hv);
            if (L == 2 && tbase + k == SEQ - 1)
                out[(size_t)(grow0 + rq * 4 + j) * 512 + d * 256 + (ct0 + c) * 16 + colw] = hv;
        }

        if constexpr (L < 2) { anp0 = an0; anp1 = an1; }
        zc = za; za = zb; zb = zd;

        __builtin_amdgcn_sched_barrier(0);
        asm volatile("s_waitcnt lgkmcnt(0)" ::: "memory");
        __builtin_amdgcn_s_barrier();
        __builtin_amdgcn_sched_barrier(0);
    }

    if constexpr (L < 2) {
        // emit slot CH-2 (from last iteration's an)
        {
            uint4 sv;
            sv.x = pk2(anp0[0], anp0[1]); sv.y = pk2(anp0[2], anp0[3]);
            sv.z = pk2(anp1[0], anp1[1]); sv.w = pk2(anp1[2], anp1[3]);
            *(uint4*)(zdb + (size_t)(CH - 2) * ZTILE + zoff) = sv;
        }
        // tail GEMM for slot CH-1 from final h (buffer 1)
        f32x4 an0 = (f32x4){bn0, bn0, bn0, bn0};
        f32x4 an1 = (f32x4){bn1, bn1, bn1, bn1};
        #pragma unroll
        for (int kt = 0; kt < 8; ++kt) {
            const f16x8 ah = *(const f16x8*)&Hb[4224 + colw * 264 + kt * 32 + rq8];
            an0 = __builtin_amdgcn_mfma_f32_16x16x32_f16(ah, wn0[kt], an0, 0, 0, 0);
            an1 = __builtin_amdgcn_mfma_f32_16x16x32_f16(ah, wn1[kt], an1, 0, 0, 0);
        }
        uint4 sv;
        sv.x = pk2(an0[0], an0[1]); sv.y = pk2(an0[2], an0[3]);
        sv.z = pk2(an1[0], an1[1]); sv.w = pk2(an1[2], an1[3]);
        *(uint4*)(zdb + (size_t)(CH - 1) * ZTILE + zoff) = sv;
    }
    // h carry out (final h in buffer 1; CH even)
    {
        uint16_t* hc = hcarry + (size_t)(d * 3 + L) * 131072;
        const int row = tid >> 5, c8 = (tid & 31) * 8;
        *(uint4*)(hc + (size_t)(grow0 + row) * 256 + c8) = *(const uint4*)&Hb[4224 + row * 264 + c8];
    }
}

__global__ __attribute__((amdgpu_flat_work_group_size(NT, NT), amdgpu_waves_per_eu(2, 2)))
void rnn_pipe(const _Float16* whh_all,
              const _Float16* wihn_all,
              uint16_t* z0, uint16_t* z1, uint16_t* z2,
              uint16_t* hcarry,
              const float* fb, const float* bb,
              float* out, int slot)
{
    __shared__ uint16_t Hb[2 * 16 * 264];
    const int l = blockIdx.x >> 6, sub = blockIdx.x & 63;
    const int d = sub >> 5, i = sub & 31;
    const int cs = slot - l;
    if (cs < 0 || cs >= NCH) return;
    if (l == 0)      pipe_run<0>(whh_all, wihn_all, z0, z1, hcarry, fb, bb, out, d, i, cs, Hb);
    else if (l == 1) pipe_run<1>(whh_all, wihn_all, z1, z2, hcarry, fb, bb, out, d, i, cs, Hb);
    else             pipe_run<2>(whh_all, wihn_all, z2, nullptr, hcarry, fb, bb, out, d, i, cs, Hb);
}

extern "C" void kernel_launch(void* const* d_in, const int* in_sizes, int n_in,
                              void* d_out, int out_size, void* d_ws, size_t ws_size,
                              hipStream_t stream)
{
    (void)in_sizes; (void)n_in; (void)out_size; (void)ws_size;
    const float* x      = (const float*)d_in[0];
    const float* fW_ih0 = (const float*)d_in[1];
    const float* fW_ih  = (const float*)d_in[2];
    const float* fW_hh  = (const float*)d_in[3];
    const float* fb     = (const float*)d_in[4];
    const float* bW_ih0 = (const float*)d_in[5];
    const float* bW_ih  = (const float*)d_in[6];
    const float* bW_hh  = (const float*)d_in[7];
    const float* bb     = (const float*)d_in[8];
    uint8_t* ws = (uint8_t*)d_ws;

    _Float16* wf     = (_Float16*)ws;
    uint16_t* hcarry = (uint16_t*)(ws + HC_BYTE);
    uint16_t* z0     = (uint16_t*)(ws + Z_BYTE);
    uint16_t* z1     = z0 + ZBUF_E;
    uint16_t* z2     = z1 + ZBUF_E;
    const _Float16* whh  = wf + WHH_E;
    const _Float16* wihn = wf + WIHN_E;
    float* out = (float*)d_out;

    rnn_prep<<<400, 256, 0, stream>>>(fW_ih0, fW_ih, fW_hh, bW_ih0, bW_ih, bW_hh, wf);
    rnn_gemm0<<<512, NT, 0, stream>>>(x, wf, fb, bb, z0);
    for (int s = 0; s < NSLOT; ++s)
        rnn_pipe<<<192, NT, 0, stream>>>(whh, wihn, z0, z1, z2, hcarry, fb, bb, out, s);
}

// Round 9
// 1072.344 us; speedup vs baseline: 1.2762x; 1.0190x over previous
//
#include <hip/hip_runtime.h>
#include <cstdint>
#include <cstddef>

// Bidirectional 3-layer tanh RNN, S=512 B=512 D=300 H=256.
// R9: rec slimmed to recurrent-only step loop (asm-pinned Whh in VGPRs,
//     XOR-swizzled LDS h tile) + in-kernel phase-2 bulk GEMM producing the
//     next layer's Zin from the h history (global round-trip, LDS re-frag).
//     gemm0 rebuilt: 16-row tiles, 2 blocks/CU, reg-pipelined x staging.
//     z1/z2 are 2-chunk rings (L3-resident).

#define SEQ   512
#define BATCH 512
#define DIN   300
#define HDIM  256
#define NT    512
#define CH    64
#define NCH   (SEQ / CH)    // 8
#define NSLOT (NCH + 2)     // 10
#define TS    16
#define ZTILE 131072        // u16 per (d,t) tile (512 rows x 256 cols)

typedef _Float16 f16x8 __attribute__((ext_vector_type(8)));
typedef __fp16   fp16x2 __attribute__((ext_vector_type(2)));
typedef float    f32x4 __attribute__((ext_vector_type(4)));

// ---- ws layout ----
// f16-element offsets:
#define WIH0_E 0            // [2 dir][16ct][10kt][64][8]
#define WHH_E  163840       // [2][3 layer][16ct][8kt][64][8]
#define WIHN_E 557056       // [2][2 (->l1,l2)][16ct][8kt][64][8]
// byte offsets:
#define HC_BYTE   1638400                    // u16 [2d][3l][512][256]
#define HB_BYTE   3211264                    // h history: 4 regions x 8388608 u16
#define HB_REG_E  8388608ull
#define Z0_BYTE   (HB_BYTE + 67108864)       // 70320128; full [2][512] tiles
#define Z1_BYTE   (Z0_BYTE + 268435456)      // ring: [2 ring][2 d][64 t] tiles
#define Z2_BYTE   (Z1_BYTE + 67108864)
// end = 472973312 bytes

static __device__ __forceinline__ uint16_t f16bits(_Float16 h) {
    union { _Float16 h; uint16_t u; } v; v.h = h; return v.u;
}
static __device__ __forceinline__ uint32_t pk2(float a, float b) {
    union { fp16x2 h; uint32_t u; } v; v.h = __builtin_amdgcn_cvt_pkrtz(a, b); return v.u;
}
static __device__ __forceinline__ int swz(int row, int col) {   // u16-index swizzle
    return (row * 256 + col) ^ ((row & 7) << 3);
}

// 8 fragment loads in one volatile asm (results CANNOT be rematerialized)
static __device__ __forceinline__ void aload8(f16x8 r[8], const _Float16* p, size_t stepE) {
    const _Float16* p0 = p;
    const _Float16* p1 = p + stepE;
    const _Float16* p2 = p + 2 * stepE;
    const _Float16* p3 = p + 3 * stepE;
    const _Float16* p4 = p + 4 * stepE;
    const _Float16* p5 = p + 5 * stepE;
    const _Float16* p6 = p + 6 * stepE;
    const _Float16* p7 = p + 7 * stepE;
    asm volatile(
        "global_load_dwordx4 %0, %8, off\n\t"
        "global_load_dwordx4 %1, %9, off\n\t"
        "global_load_dwordx4 %2, %10, off\n\t"
        "global_load_dwordx4 %3, %11, off\n\t"
        "global_load_dwordx4 %4, %12, off\n\t"
        "global_load_dwordx4 %5, %13, off\n\t"
        "global_load_dwordx4 %6, %14, off\n\t"
        "global_load_dwordx4 %7, %15, off\n\t"
        "s_waitcnt vmcnt(0)"
        : "=&v"(r[0]), "=&v"(r[1]), "=&v"(r[2]), "=&v"(r[3]),
          "=&v"(r[4]), "=&v"(r[5]), "=&v"(r[6]), "=&v"(r[7])
        : "v"(p0), "v"(p1), "v"(p2), "v"(p3), "v"(p4), "v"(p5), "v"(p6), "v"(p7)
        : "memory");
}

// ---------------- prep: weights -> f16 fragment layout ----------------
__global__ void rnn_prep(const float* __restrict__ fW_ih0, const float* __restrict__ fW_ih,
                         const float* __restrict__ fW_hh,  const float* __restrict__ bW_ih0,
                         const float* __restrict__ bW_ih,  const float* __restrict__ bW_hh,
                         _Float16* __restrict__ wf)
{
    const int gid = blockIdx.x * 256 + threadIdx.x;   // 0..102399
    const int d = gid / 51200;
    const int r = gid - d * 51200;
    const int lane = r & 63;
    const float* Wih0 = d ? bW_ih0 : fW_ih0;
    const float* Wih  = d ? bW_ih  : fW_ih;
    const float* Whh  = d ? bW_hh  : fW_hh;
    _Float16 vals[8];
    size_t dstE;
    if (r < 10240) {                       // W_ih0 frags, K=320 padded
        const int ck = r >> 6, ct = ck / 10, kt = ck - ct * 10;
        const int col = ct * 16 + (lane & 15);
        const int k0  = kt * 32 + (lane >> 4) * 8;
        #pragma unroll
        for (int e = 0; e < 8; ++e) {
            const int k = k0 + e;
            vals[e] = (k < 300) ? (_Float16)Wih0[(size_t)k * 256 + col] : (_Float16)0.f;
        }
        dstE = (size_t)WIH0_E + (size_t)d * 81920 + (size_t)r * 8;
    } else if (r < 34816) {                // W_hh frags
        const int rr = r - 10240, l = rr / 8192, r2 = rr - l * 8192;
        const int ck = r2 >> 6, ct = ck >> 3, kt = ck & 7;
        const int col = ct * 16 + (lane & 15);
        const int k0  = kt * 32 + (lane >> 4) * 8;
        #pragma unroll
        for (int e = 0; e < 8; ++e)
            vals[e] = (_Float16)Whh[((size_t)(l * 256 + k0 + e)) * 256 + col];
        dstE = (size_t)WHH_E + (size_t)(d * 3 + l) * 65536 + (size_t)r2 * 8;
    } else {                               // W_ih layers 1,2 frags
        const int rr = r - 34816, ln = rr / 8192, r2 = rr - ln * 8192;
        const int ck = r2 >> 6, ct = ck >> 3, kt = ck & 7;
        const int col = ct * 16 + (lane & 15);
        const int k0  = kt * 32 + (lane >> 4) * 8;
        #pragma unroll
        for (int e = 0; e < 8; ++e)
            vals[e] = (_Float16)Wih[((size_t)(ln * 256 + k0 + e)) * 256 + col];
        dstE = (size_t)WIHN_E + (size_t)(d * 2 + ln) * 65536 + (size_t)r2 * 8;
    }
    *(f16x8*)(wf + dstE) = *(const f16x8*)vals;
}

// ---------------- gemm0: Zin0 = x @ W_ih0 + b0 ----------------
// 1024 blocks = 32 sg x 32 rb(16 rows), both dirs, TS=16 steps each.
// x staged via regs-then-LDS (loads issued before MFMA phase); weights streamed.
__global__ __attribute__((amdgpu_flat_work_group_size(NT, NT)))
void rnn_gemm0(const float* __restrict__ x, const _Float16* __restrict__ wih0,
               const float* __restrict__ fb, const float* __restrict__ bb,
               uint16_t* __restrict__ z0)
{
    __shared__ uint16_t Xl[2][16 * 332];   // 2 x 10.6 KB
    const int tid = threadIdx.x, lane = tid & 63, w = tid >> 6;
    const int colw = lane & 15, rq = lane >> 4, rq8 = rq * 8;
    const int ct0 = w * 2;
    const int sg = blockIdx.x >> 5, rb = blockIdx.x & 31;
    const int b0 = rb * 16;
    const size_t chunk = ((size_t)(rb * 8 + w) * 64 + lane) * 8;

    int rs[5], cc2[5]; bool pv[5];
    #pragma unroll
    for (int b = 0; b < 5; ++b) {
        const int p = tid + b * NT;
        pv[b] = p < 2400;                  // 16 rows x 150 float2
        const int r = p / 150;
        rs[b] = r; cc2[b] = (p - r * 150) * 2;
    }

    float bv[2][2];
    #pragma unroll
    for (int dd = 0; dd < 2; ++dd)
        #pragma unroll
        for (int c = 0; c < 2; ++c)
            bv[dd][c] = (dd ? bb : fb)[(ct0 + c) * 16 + colw];

    for (int p = tid; p < 320; p += NT) {  // zero pad k in [300,320), both buffers
        const int bu = p / 160, q = p - bu * 160;
        const int r = q / 10, cc = 300 + (q - r * 10) * 2;
        *(uint32_t*)&Xl[bu][r * 332 + cc] = 0;
    }
    {   // stage si=0
        const float* xs = x + ((size_t)(sg * TS) * BATCH + b0) * DIN;
        #pragma unroll
        for (int b = 0; b < 5; ++b) if (pv[b]) {
            const float2 v = *(const float2*)(xs + (size_t)rs[b] * DIN + cc2[b]);
            *(uint32_t*)&Xl[0][rs[b] * 332 + cc2[b]] = pk2(v.x, v.y);
        }
    }
    __syncthreads();

    #pragma unroll 1
    for (int si = 0; si < TS; ++si) {
        const int s = sg * TS + si;
        const int buf = si & 1;
        const bool last = (si == TS - 1);

        // ---- dir 0 ----
        {
            f32x4 a0 = (f32x4){bv[0][0], bv[0][0], bv[0][0], bv[0][0]};
            f32x4 a1 = (f32x4){bv[0][1], bv[0][1], bv[0][1], bv[0][1]};
            #pragma unroll
            for (int kt = 0; kt < 10; ++kt) {
                const f16x8 wv0 = *(const f16x8*)(wih0 + (((size_t)ct0 * 10 + kt) * 64 + lane) * 8);
                const f16x8 wv1 = *(const f16x8*)(wih0 + (((size_t)(ct0 + 1) * 10 + kt) * 64 + lane) * 8);
                const f16x8 a = *(const f16x8*)&Xl[buf][colw * 332 + kt * 32 + rq8];
                a0 = __builtin_amdgcn_mfma_f32_16x16x32_f16(a, wv0, a0, 0, 0, 0);
                a1 = __builtin_amdgcn_mfma_f32_16x16x32_f16(a, wv1, a1, 0, 0, 0);
            }
            uint4 sv;
            sv.x = pk2(a0[0], a0[1]); sv.y = pk2(a0[2], a0[3]);
            sv.z = pk2(a1[0], a1[1]); sv.w = pk2(a1[2], a1[3]);
            *(uint4*)(z0 + (size_t)s * ZTILE + chunk) = sv;
        }

        // ---- issue x loads for si+1 (latency hides under dir-1 MFMAs) ----
        float2 xr[5];
        if (!last) {
            const float* xs = x + ((size_t)(s + 1) * BATCH + b0) * DIN;
            #pragma unroll
            for (int b = 0; b < 5; ++b) if (pv[b])
                xr[b] = *(const float2*)(xs + (size_t)rs[b] * DIN + cc2[b]);
        }

        // ---- dir 1 ----
        f32x4 a0 = (f32x4){bv[1][0], bv[1][0], bv[1][0], bv[1][0]};
        f32x4 a1 = (f32x4){bv[1][1], bv[1][1], bv[1][1], bv[1][1]};
        #pragma unroll
        for (int kt = 0; kt < 10; ++kt) {
            const f16x8 wv0 = *(const f16x8*)(wih0 + 81920 + (((size_t)ct0 * 10 + kt) * 64 + lane) * 8);
            const f16x8 wv1 = *(const f16x8*)(wih0 + 81920 + (((size_t)(ct0 + 1) * 10 + kt) * 64 + lane) * 8);
            const f16x8 a = *(const f16x8*)&Xl[buf][colw * 332 + kt * 32 + rq8];
            a0 = __builtin_amdgcn_mfma_f32_16x16x32_f16(a, wv0, a0, 0, 0, 0);
            a1 = __builtin_amdgcn_mfma_f32_16x16x32_f16(a, wv1, a1, 0, 0, 0);
        }

        // ---- write staged x to other LDS buffer ----
        if (!last) {
            #pragma unroll
            for (int b = 0; b < 5; ++b) if (pv[b])
                *(uint32_t*)&Xl[buf ^ 1][rs[b] * 332 + cc2[b]] = pk2(xr[b].x, xr[b].y);
        }

        // ---- dir-1 z store (stays in flight across barrier) ----
        {
            uint4 sv;
            sv.x = pk2(a0[0], a0[1]); sv.y = pk2(a0[2], a0[3]);
            sv.z = pk2(a1[0], a1[1]); sv.w = pk2(a1[2], a1[3]);
            *(uint4*)(z0 + ((size_t)SEQ + (SEQ - 1 - s)) * ZTILE + chunk) = sv;
        }

        __builtin_amdgcn_sched_barrier(0);
        asm volatile("s_waitcnt lgkmcnt(0)" ::: "memory");
        __builtin_amdgcn_s_barrier();
        __builtin_amdgcn_sched_barrier(0);
    }
}

// ---------------- rec<L>: recurrent steps + phase-2 next-layer GEMM ----------------
template<int L>
__device__ __forceinline__ void rec_run(const _Float16* whh_all, const _Float16* wihn_all,
                                        const uint16_t* zsrc, uint16_t* zdst,
                                        uint16_t* hcarry, uint16_t* hbuf,
                                        const float* fb, const float* bb,
                                        float* out, int d, int i, int cs, uint16_t* Hb)
{
    const int tid = threadIdx.x, lane = tid & 63, w = tid >> 6;
    const int colw = lane & 15, rq = lane >> 4, rq8 = rq * 8;
    const int ct0 = w * 2;
    const int grow0 = i * 16;

    // ---- recurrent weights: asm-pinned ----
    const _Float16* whh = whh_all + (size_t)(d * 3 + L) * 65536;
    f16x8 wh0[8], wh1[8];
    aload8(wh0, whh + ((size_t)ct0 * 8 * 64 + lane) * 8, 512);
    aload8(wh1, whh + ((size_t)(ct0 + 1) * 8 * 64 + lane) * 8, 512);

    // ---- init h LDS (zero; carry into buffer 1) ----
    for (int p = tid; p < 4096; p += NT) ((uint32_t*)Hb)[p] = 0;
    __syncthreads();
    if (cs > 0) {
        const uint16_t* hc = hcarry + (size_t)(d * 3 + L) * 131072;
        const int row = tid >> 5, c8 = (tid & 31) * 8;
        *(uint4*)&Hb[4096 + ((row * 256 + c8) ^ ((row & 7) << 3))] =
            *(const uint4*)(hc + (size_t)(grow0 + row) * 256 + c8);
    }
    __syncthreads();

    const size_t zoff = ((size_t)(i * 8 + w) * 64 + lane) * 8;
    uint16_t* hbp = nullptr;
    if constexpr (L < 2) hbp = hbuf + (size_t)(L * 2 + d) * HB_REG_E;

    uint4 zc = *(const uint4*)(zsrc + zoff);
    uint4 za = *(const uint4*)(zsrc + (size_t)ZTILE + zoff);
    uint4 zb = *(const uint4*)(zsrc + 2 * (size_t)ZTILE + zoff);

    // ---- phase 1: CH recurrent steps ----
    #pragma unroll 1
    for (int k = 0; k < CH; ++k) {
        const int cur = k & 1, prv = cur ^ 1;
        const int kp = (k + 3 < CH) ? (k + 3) : (CH - 1);
        const uint4 zd = *(const uint4*)(zsrc + (size_t)kp * ZTILE + zoff);

        f16x8 ah[8];
        #pragma unroll
        for (int kt = 0; kt < 8; ++kt)
            ah[kt] = *(const f16x8*)&Hb[(prv << 12) + swz(colw, kt * 32 + rq8)];

        f32x4 ar0, ar1;
        {
            union { uint4 u; _Float16 h[8]; } zz; zz.u = zc;
            ar0 = (f32x4){(float)zz.h[0], (float)zz.h[1], (float)zz.h[2], (float)zz.h[3]};
            ar1 = (f32x4){(float)zz.h[4], (float)zz.h[5], (float)zz.h[6], (float)zz.h[7]};
        }
        #pragma unroll
        for (int kt = 0; kt < 8; ++kt) {
            ar0 = __builtin_amdgcn_mfma_f32_16x16x32_f16(ah[kt], wh0[kt], ar0, 0, 0, 0);
            ar1 = __builtin_amdgcn_mfma_f32_16x16x32_f16(ah[kt], wh1[kt], ar1, 0, 0, 0);
        }

        float hv[8];
        #pragma unroll
        for (int q = 0; q < 8; ++q) {
            const float S = (q < 4) ? ar0[q] : ar1[q - 4];
            const float e = __builtin_amdgcn_exp2f(S * 2.885390081777927f);
            const float r = __builtin_amdgcn_rcpf(e + 1.f);
            hv[q] = __builtin_fmaf(-2.f, r, 1.f);
        }
        #pragma unroll
        for (int q = 0; q < 8; ++q) {
            const int c = q >> 2, j = q & 3;
            Hb[(cur << 12) + swz(rq * 4 + j, (ct0 + c) * 16 + colw)] = f16bits((_Float16)hv[q]);
        }
        if constexpr (L < 2) {
            uint4 sv;
            sv.x = pk2(hv[0], hv[1]); sv.y = pk2(hv[2], hv[3]);
            sv.z = pk2(hv[4], hv[5]); sv.w = pk2(hv[6], hv[7]);
            *(uint4*)(hbp + (size_t)k * ZTILE + zoff) = sv;   // h history (MFMA shadow)
        } else if (cs == NCH - 1 && k == CH - 1) {
            #pragma unroll
            for (int q = 0; q < 8; ++q) {
                const int c = q >> 2, j = q & 3;
                out[(size_t)(grow0 + rq * 4 + j) * 512 + d * 256 + (ct0 + c) * 16 + colw] = hv[q];
            }
        }

        zc = za; za = zb; zb = zd;

        __builtin_amdgcn_sched_barrier(0);
        asm volatile("s_waitcnt lgkmcnt(0)" ::: "memory");
        __builtin_amdgcn_s_barrier();
        __builtin_amdgcn_sched_barrier(0);
    }

    // ---- h carry out (final h in buffer 1; CH even) ----
    {
        uint16_t* hc = hcarry + (size_t)(d * 3 + L) * 131072;
        const int row = tid >> 5, c8 = (tid & 31) * 8;
        *(uint4*)(hc + (size_t)(grow0 + row) * 256 + c8) =
            *(const uint4*)&Hb[4096 + ((row * 256 + c8) ^ ((row & 7) << 3))];
    }

    // ---- phase 2: Zin_{L+1} = H @ Wih_{L+1} + b_{L+1} over the whole chunk ----
    if constexpr (L < 2) {
        __syncthreads();   // drains h-history stores (vmcnt) + carry-out read

        const _Float16* wnx = wihn_all + (size_t)(d * 2 + L) * 65536;
        f16x8 wn0[8], wn1[8];
        aload8(wn0, wnx + ((size_t)ct0 * 8 * 64 + lane) * 8, 512);
        aload8(wn1, wnx + ((size_t)(ct0 + 1) * 8 * 64 + lane) * 8, 512);
        const float* bnx = (d ? bb : fb) + (L + 1) * HDIM;
        const float bn0 = bnx[ct0 * 16 + colw];
        const float bn1 = bnx[(ct0 + 1) * 16 + colw];

        {   // stage t=0
            union { uint4 u; uint16_t s[8]; } hz;
            hz.u = *(const uint4*)(hbp + zoff);
            #pragma unroll
            for (int q = 0; q < 8; ++q) {
                const int c = q >> 2, j = q & 3;
                Hb[swz(rq * 4 + j, (ct0 + c) * 16 + colw)] = hz.s[q];
            }
        }
        __syncthreads();

        #pragma unroll 1
        for (int t = 0; t < CH; ++t) {
            const int buf = t & 1;
            uint4 hn;
            if (t < CH - 1) hn = *(const uint4*)(hbp + (size_t)(t + 1) * ZTILE + zoff);

            f16x8 ax[8];
            #pragma unroll
            for (int kt = 0; kt < 8; ++kt)
                ax[kt] = *(const f16x8*)&Hb[(buf << 12) + swz(colw, kt * 32 + rq8)];

            f32x4 an0 = (f32x4){bn0, bn0, bn0, bn0};
            f32x4 an1 = (f32x4){bn1, bn1, bn1, bn1};
            #pragma unroll
            for (int kt = 0; kt < 8; ++kt) {
                an0 = __builtin_amdgcn_mfma_f32_16x16x32_f16(ax[kt], wn0[kt], an0, 0, 0, 0);
                an1 = __builtin_amdgcn_mfma_f32_16x16x32_f16(ax[kt], wn1[kt], an1, 0, 0, 0);
            }

            if (t < CH - 1) {   // stage t+1 into other buffer
                union { uint4 u; uint16_t s[8]; } hz; hz.u = hn;
                #pragma unroll
                for (int q = 0; q < 8; ++q) {
                    const int c = q >> 2, j = q & 3;
                    Hb[((buf ^ 1) << 12) + swz(rq * 4 + j, (ct0 + c) * 16 + colw)] = hz.s[q];
                }
            }

            uint4 sv;
            sv.x = pk2(an0[0], an0[1]); sv.y = pk2(an0[2], an0[3]);
            sv.z = pk2(an1[0], an1[1]); sv.w = pk2(an1[2], an1[3]);
            *(uint4*)(zdst + (size_t)t * ZTILE + zoff) = sv;

            __builtin_amdgcn_sched_barrier(0);
            asm volatile("s_waitcnt lgkmcnt(0)" ::: "memory");
            __builtin_amdgcn_s_barrier();
            __builtin_amdgcn_sched_barrier(0);
        }
    }
}

__global__ __attribute__((amdgpu_flat_work_group_size(NT, NT), amdgpu_waves_per_eu(2)))
void rnn_rec(const _Float16* whh_all, const _Float16* wihn_all,
             uint16_t* z0, uint16_t* z1, uint16_t* z2,
             uint16_t* hcarry, uint16_t* hbuf,
             const float* fb, const float* bb, float* out, int slot)
{
    __shared__ uint16_t Hb[2 * 4096];
    const int l = blockIdx.x >> 6, sub = blockIdx.x & 63;
    const int d = sub >> 5, i = sub & 31;
    const int cs = slot - l;
    if (cs < 0 || cs >= NCH) return;
    const size_t ringE = (size_t)((cs & 1) * 2 + d) * HB_REG_E;
    if (l == 0) {
        const uint16_t* zs = z0 + ((size_t)d * SEQ + (size_t)cs * CH) * ZTILE;
        rec_run<0>(whh_all, wihn_all, zs, z1 + ringE, hcarry, hbuf, fb, bb, out, d, i, cs, Hb);
    } else if (l == 1) {
        rec_run<1>(whh_all, wihn_all, z1 + ringE, z2 + ringE, hcarry, hbuf, fb, bb, out, d, i, cs, Hb);
    } else {
        rec_run<2>(whh_all, wihn_all, z2 + ringE, nullptr, hcarry, hbuf, fb, bb, out, d, i, cs, Hb);
    }
}

extern "C" void kernel_launch(void* const* d_in, const int* in_sizes, int n_in,
                              void* d_out, int out_size, void* d_ws, size_t ws_size,
                              hipStream_t stream)
{
    (void)in_sizes; (void)n_in; (void)out_size; (void)ws_size;
    const float* x      = (const float*)d_in[0];
    const float* fW_ih0 = (const float*)d_in[1];
    const float* fW_ih  = (const float*)d_in[2];
    const float* fW_hh  = (const float*)d_in[3];
    const float* fb     = (const float*)d_in[4];
    const float* bW_ih0 = (const float*)d_in[5];
    const float* bW_ih  = (const float*)d_in[6];
    const float* bW_hh  = (const float*)d_in[7];
    const float* bb     = (const float*)d_in[8];
    uint8_t* ws = (uint8_t*)d_ws;

    _Float16* wf     = (_Float16*)ws;
    uint16_t* hcarry = (uint16_t*)(ws + HC_BYTE);
    uint16_t* hbuf   = (uint16_t*)(ws + HB_BYTE);
    uint16_t* z0     = (uint16_t*)(ws + Z0_BYTE);
    uint16_t* z1     = (uint16_t*)(ws + Z1_BYTE);
    uint16_t* z2     = (uint16_t*)(ws + Z2_BYTE);
    const _Float16* whh  = wf + WHH_E;
    const _Float16* wihn = wf + WIHN_E;
    float* out = (float*)d_out;

    rnn_prep<<<400, 256, 0, stream>>>(fW_ih0, fW_ih, fW_hh, bW_ih0, bW_ih, bW_hh, wf);
    rnn_gemm0<<<1024, NT, 0, stream>>>(x, wf, fb, bb, z0);
    for (int s = 0; s < NSLOT; ++s)
        rnn_rec<<<192, NT, 0, stream>>>(whh, wihn, z0, z1, z2, hcarry, hbuf, fb, bb, out, s);
}

// Round 10
// 872.900 us; speedup vs baseline: 1.5678x; 1.2285x over previous
//
#include <hip/hip_runtime.h>
#include <cstdint>
#include <cstddef>

// Bidirectional 3-layer tanh RNN, S=512 B=512 D=300 H=256.
// R10: fused rec step (32 MFMA, ONE barrier/step) with volatile-asm-pinned
//      weights (128 VGPR, cannot be rematerialized), waves_per_eu(2) for the
//      256-VGPR budget. XOR-swizzled LDS h tile, lane-chunked z (16B/lane),
//      3-deep z prefetch, lgkm-only barrier. Phase-2 / h-history removed.
//      gemm0: R9's reg-pipelined 16-row-tile version (x read once).

#define SEQ   512
#define BATCH 512
#define DIN   300
#define HDIM  256
#define NT    512
#define CH    64
#define NCH   (SEQ / CH)    // 8
#define NSLOT (NCH + 2)     // 10
#define TS    16
#define ZTILE 131072        // u16 per (d,t) tile (512 rows x 256 cols)

typedef _Float16 f16x8 __attribute__((ext_vector_type(8)));
typedef __fp16   fp16x2 __attribute__((ext_vector_type(2)));
typedef float    f32x4 __attribute__((ext_vector_type(4)));

// ---- ws layout (byte/element offsets kept from R9; hbuf region now unused) ----
#define WIH0_E 0            // f16 [2 dir][16ct][10kt][64][8]
#define WHH_E  163840       // f16 [2][3 layer][16ct][8kt][64][8]
#define WIHN_E 557056       // f16 [2][2 (->l1,l2)][16ct][8kt][64][8]
#define HC_BYTE   1638400   // u16 [2d][3l][512][256]
#define HB_BYTE   3211264
#define Z0_BYTE   (HB_BYTE + 67108864)
#define Z1_BYTE   (Z0_BYTE + 268435456)
#define Z2_BYTE   (Z1_BYTE + 67108864)
#define RING_E    8388608ull   // u16 per ring region (CH tiles)

static __device__ __forceinline__ uint16_t f16bits(_Float16 h) {
    union { _Float16 h; uint16_t u; } v; v.h = h; return v.u;
}
static __device__ __forceinline__ uint32_t pk2(float a, float b) {
    union { fp16x2 h; uint32_t u; } v; v.h = __builtin_amdgcn_cvt_pkrtz(a, b); return v.u;
}
static __device__ __forceinline__ int swz(int row, int col) {   // u16-index swizzle
    return (row * 256 + col) ^ ((row & 7) << 3);
}

// 8 fragment loads in one volatile asm (results CANNOT be rematerialized)
static __device__ __forceinline__ void aload8(f16x8 r[8], const _Float16* p, size_t stepE) {
    const _Float16* p0 = p;
    const _Float16* p1 = p + stepE;
    const _Float16* p2 = p + 2 * stepE;
    const _Float16* p3 = p + 3 * stepE;
    const _Float16* p4 = p + 4 * stepE;
    const _Float16* p5 = p + 5 * stepE;
    const _Float16* p6 = p + 6 * stepE;
    const _Float16* p7 = p + 7 * stepE;
    asm volatile(
        "global_load_dwordx4 %0, %8, off\n\t"
        "global_load_dwordx4 %1, %9, off\n\t"
        "global_load_dwordx4 %2, %10, off\n\t"
        "global_load_dwordx4 %3, %11, off\n\t"
        "global_load_dwordx4 %4, %12, off\n\t"
        "global_load_dwordx4 %5, %13, off\n\t"
        "global_load_dwordx4 %6, %14, off\n\t"
        "global_load_dwordx4 %7, %15, off\n\t"
        "s_waitcnt vmcnt(0)"
        : "=&v"(r[0]), "=&v"(r[1]), "=&v"(r[2]), "=&v"(r[3]),
          "=&v"(r[4]), "=&v"(r[5]), "=&v"(r[6]), "=&v"(r[7])
        : "v"(p0), "v"(p1), "v"(p2), "v"(p3), "v"(p4), "v"(p5), "v"(p6), "v"(p7)
        : "memory");
}

// ---------------- prep: weights -> f16 fragment layout ----------------
__global__ void rnn_prep(const float* __restrict__ fW_ih0, const float* __restrict__ fW_ih,
                         const float* __restrict__ fW_hh,  const float* __restrict__ bW_ih0,
                         const float* __restrict__ bW_ih,  const float* __restrict__ bW_hh,
                         _Float16* __restrict__ wf)
{
    const int gid = blockIdx.x * 256 + threadIdx.x;   // 0..102399
    const int d = gid / 51200;
    const int r = gid - d * 51200;
    const int lane = r & 63;
    const float* Wih0 = d ? bW_ih0 : fW_ih0;
    const float* Wih  = d ? bW_ih  : fW_ih;
    const float* Whh  = d ? bW_hh  : fW_hh;
    _Float16 vals[8];
    size_t dstE;
    if (r < 10240) {                       // W_ih0 frags, K=320 padded
        const int ck = r >> 6, ct = ck / 10, kt = ck - ct * 10;
        const int col = ct * 16 + (lane & 15);
        const int k0  = kt * 32 + (lane >> 4) * 8;
        #pragma unroll
        for (int e = 0; e < 8; ++e) {
            const int k = k0 + e;
            vals[e] = (k < 300) ? (_Float16)Wih0[(size_t)k * 256 + col] : (_Float16)0.f;
        }
        dstE = (size_t)WIH0_E + (size_t)d * 81920 + (size_t)r * 8;
    } else if (r < 34816) {                // W_hh frags
        const int rr = r - 10240, l = rr / 8192, r2 = rr - l * 8192;
        const int ck = r2 >> 6, ct = ck >> 3, kt = ck & 7;
        const int col = ct * 16 + (lane & 15);
        const int k0  = kt * 32 + (lane >> 4) * 8;
        #pragma unroll
        for (int e = 0; e < 8; ++e)
            vals[e] = (_Float16)Whh[((size_t)(l * 256 + k0 + e)) * 256 + col];
        dstE = (size_t)WHH_E + (size_t)(d * 3 + l) * 65536 + (size_t)r2 * 8;
    } else {                               // W_ih layers 1,2 frags
        const int rr = r - 34816, ln = rr / 8192, r2 = rr - ln * 8192;
        const int ck = r2 >> 6, ct = ck >> 3, kt = ck & 7;
        const int col = ct * 16 + (lane & 15);
        const int k0  = kt * 32 + (lane >> 4) * 8;
        #pragma unroll
        for (int e = 0; e < 8; ++e)
            vals[e] = (_Float16)Wih[((size_t)(ln * 256 + k0 + e)) * 256 + col];
        dstE = (size_t)WIHN_E + (size_t)(d * 2 + ln) * 65536 + (size_t)r2 * 8;
    }
    *(f16x8*)(wf + dstE) = *(const f16x8*)vals;
}

// ---------------- gemm0: Zin0 = x @ W_ih0 + b0 (R9 version) ----------------
__global__ __attribute__((amdgpu_flat_work_group_size(NT, NT)))
void rnn_gemm0(const float* __restrict__ x, const _Float16* __restrict__ wih0,
               const float* __restrict__ fb, const float* __restrict__ bb,
               uint16_t* __restrict__ z0)
{
    __shared__ uint16_t Xl[2][16 * 332];
    const int tid = threadIdx.x, lane = tid & 63, w = tid >> 6;
    const int colw = lane & 15, rq = lane >> 4, rq8 = rq * 8;
    const int ct0 = w * 2;
    const int sg = blockIdx.x >> 5, rb = blockIdx.x & 31;
    const int b0 = rb * 16;
    const size_t chunk = ((size_t)(rb * 8 + w) * 64 + lane) * 8;

    int rs[5], cc2[5]; bool pv[5];
    #pragma unroll
    for (int b = 0; b < 5; ++b) {
        const int p = tid + b * NT;
        pv[b] = p < 2400;
        const int r = p / 150;
        rs[b] = r; cc2[b] = (p - r * 150) * 2;
    }

    float bv[2][2];
    #pragma unroll
    for (int dd = 0; dd < 2; ++dd)
        #pragma unroll
        for (int c = 0; c < 2; ++c)
            bv[dd][c] = (dd ? bb : fb)[(ct0 + c) * 16 + colw];

    for (int p = tid; p < 320; p += NT) {
        const int bu = p / 160, q = p - bu * 160;
        const int r = q / 10, cc = 300 + (q - r * 10) * 2;
        *(uint32_t*)&Xl[bu][r * 332 + cc] = 0;
    }
    {
        const float* xs = x + ((size_t)(sg * TS) * BATCH + b0) * DIN;
        #pragma unroll
        for (int b = 0; b < 5; ++b) if (pv[b]) {
            const float2 v = *(const float2*)(xs + (size_t)rs[b] * DIN + cc2[b]);
            *(uint32_t*)&Xl[0][rs[b] * 332 + cc2[b]] = pk2(v.x, v.y);
        }
    }
    __syncthreads();

    #pragma unroll 1
    for (int si = 0; si < TS; ++si) {
        const int s = sg * TS + si;
        const int buf = si & 1;
        const bool last = (si == TS - 1);

        {   // dir 0
            f32x4 a0 = (f32x4){bv[0][0], bv[0][0], bv[0][0], bv[0][0]};
            f32x4 a1 = (f32x4){bv[0][1], bv[0][1], bv[0][1], bv[0][1]};
            #pragma unroll
            for (int kt = 0; kt < 10; ++kt) {
                const f16x8 wv0 = *(const f16x8*)(wih0 + (((size_t)ct0 * 10 + kt) * 64 + lane) * 8);
                const f16x8 wv1 = *(const f16x8*)(wih0 + (((size_t)(ct0 + 1) * 10 + kt) * 64 + lane) * 8);
                const f16x8 a = *(const f16x8*)&Xl[buf][colw * 332 + kt * 32 + rq8];
                a0 = __builtin_amdgcn_mfma_f32_16x16x32_f16(a, wv0, a0, 0, 0, 0);
                a1 = __builtin_amdgcn_mfma_f32_16x16x32_f16(a, wv1, a1, 0, 0, 0);
            }
            uint4 sv;
            sv.x = pk2(a0[0], a0[1]); sv.y = pk2(a0[2], a0[3]);
            sv.z = pk2(a1[0], a1[1]); sv.w = pk2(a1[2], a1[3]);
            *(uint4*)(z0 + (size_t)s * ZTILE + chunk) = sv;
        }

        float2 xr[5];
        if (!last) {
            const float* xs = x + ((size_t)(s + 1) * BATCH + b0) * DIN;
            #pragma unroll
            for (int b = 0; b < 5; ++b) if (pv[b])
                xr[b] = *(const float2*)(xs + (size_t)rs[b] * DIN + cc2[b]);
        }

        f32x4 a0 = (f32x4){bv[1][0], bv[1][0], bv[1][0], bv[1][0]};
        f32x4 a1 = (f32x4){bv[1][1], bv[1][1], bv[1][1], bv[1][1]};
        #pragma unroll
        for (int kt = 0; kt < 10; ++kt) {
            const f16x8 wv0 = *(const f16x8*)(wih0 + 81920 + (((size_t)ct0 * 10 + kt) * 64 + lane) * 8);
            const f16x8 wv1 = *(const f16x8*)(wih0 + 81920 + (((size_t)(ct0 + 1) * 10 + kt) * 64 + lane) * 8);
            const f16x8 a = *(const f16x8*)&Xl[buf][colw * 332 + kt * 32 + rq8];
            a0 = __builtin_amdgcn_mfma_f32_16x16x32_f16(a, wv0, a0, 0, 0, 0);
            a1 = __builtin_amdgcn_mfma_f32_16x16x32_f16(a, wv1, a1, 0, 0, 0);
        }

        if (!last) {
            #pragma unroll
            for (int b = 0; b < 5; ++b) if (pv[b])
                *(uint32_t*)&Xl[buf ^ 1][rs[b] * 332 + cc2[b]] = pk2(xr[b].x, xr[b].y);
        }

        {
            uint4 sv;
            sv.x = pk2(a0[0], a0[1]); sv.y = pk2(a0[2], a0[3]);
            sv.z = pk2(a1[0], a1[1]); sv.w = pk2(a1[2], a1[3]);
            *(uint4*)(z0 + ((size_t)SEQ + (SEQ - 1 - s)) * ZTILE + chunk) = sv;
        }

        __builtin_amdgcn_sched_barrier(0);
        asm volatile("s_waitcnt lgkmcnt(0)" ::: "memory");
        __builtin_amdgcn_s_barrier();
        __builtin_amdgcn_sched_barrier(0);
    }
}

// ---------------- fused rec<L>: one barrier per step, 32 MFMA ----------------
template<int L>
__device__ __forceinline__ void rec_run(const _Float16* whh_all, const _Float16* wihn_all,
                                        const uint16_t* zsrc, uint16_t* zdst,
                                        uint16_t* hcarry, const float* fb, const float* bb,
                                        float* out, int d, int i, int cs, uint16_t* Hb)
{
    const int tid = threadIdx.x, lane = tid & 63, w = tid >> 6;
    const int colw = lane & 15, rq = lane >> 4, rq8 = rq * 8;
    const int ct0 = w * 2;
    const int grow0 = i * 16;

    // ---- weights: asm-pinned in VGPRs ----
    const _Float16* whh = whh_all + (size_t)(d * 3 + L) * 65536;
    f16x8 wh0[8], wh1[8];
    aload8(wh0, whh + ((size_t)ct0 * 8 * 64 + lane) * 8, 512);
    aload8(wh1, whh + ((size_t)(ct0 + 1) * 8 * 64 + lane) * 8, 512);
    f16x8 wn0[8], wn1[8];
    float bn0 = 0.f, bn1 = 0.f;
    if constexpr (L < 2) {
        const _Float16* wnx = wihn_all + (size_t)(d * 2 + L) * 65536;
        aload8(wn0, wnx + ((size_t)ct0 * 8 * 64 + lane) * 8, 512);
        aload8(wn1, wnx + ((size_t)(ct0 + 1) * 8 * 64 + lane) * 8, 512);
        const float* bnx = (d ? bb : fb) + (L + 1) * HDIM;
        bn0 = bnx[ct0 * 16 + colw];
        bn1 = bnx[(ct0 + 1) * 16 + colw];
    }

    // ---- init h LDS (zero; carry into buffer 1, swizzled) ----
    for (int p = tid; p < 4096; p += NT) ((uint32_t*)Hb)[p] = 0;
    __syncthreads();
    if (cs > 0) {
        const uint16_t* hc = hcarry + (size_t)(d * 3 + L) * 131072;
        const int row = tid >> 5, c8 = (tid & 31) * 8;
        *(uint4*)&Hb[4096 + ((row * 256 + c8) ^ ((row & 7) << 3))] =
            *(const uint4*)(hc + (size_t)(grow0 + row) * 256 + c8);
    }
    __syncthreads();

    const size_t zoff = ((size_t)(i * 8 + w) * 64 + lane) * 8;

    uint4 zc = *(const uint4*)(zsrc + zoff);
    uint4 za = *(const uint4*)(zsrc + (size_t)ZTILE + zoff);
    uint4 zb = *(const uint4*)(zsrc + 2 * (size_t)ZTILE + zoff);

    f32x4 anp0 = {}, anp1 = {};

    #pragma unroll 1
    for (int k = 0; k < CH; ++k) {
        const int cur = k & 1, prv = cur ^ 1;
        const int kp = (k + 3 < CH) ? (k + 3) : (CH - 1);
        const uint4 zd = *(const uint4*)(zsrc + (size_t)kp * ZTILE + zoff);

        f16x8 ah[8];
        #pragma unroll
        for (int kt = 0; kt < 8; ++kt)
            ah[kt] = *(const f16x8*)&Hb[(prv << 12) + swz(colw, kt * 32 + rq8)];

        f32x4 ar0, ar1;
        {
            union { uint4 u; _Float16 h[8]; } zz; zz.u = zc;
            ar0 = (f32x4){(float)zz.h[0], (float)zz.h[1], (float)zz.h[2], (float)zz.h[3]};
            ar1 = (f32x4){(float)zz.h[4], (float)zz.h[5], (float)zz.h[6], (float)zz.h[7]};
        }

        f32x4 an0, an1;
        if constexpr (L < 2) {
            an0 = (f32x4){bn0, bn0, bn0, bn0};
            an1 = (f32x4){bn1, bn1, bn1, bn1};
            #pragma unroll
            for (int kt = 0; kt < 8; ++kt) {           // 4 interleaved chains
                ar0 = __builtin_amdgcn_mfma_f32_16x16x32_f16(ah[kt], wh0[kt], ar0, 0, 0, 0);
                ar1 = __builtin_amdgcn_mfma_f32_16x16x32_f16(ah[kt], wh1[kt], ar1, 0, 0, 0);
                an0 = __builtin_amdgcn_mfma_f32_16x16x32_f16(ah[kt], wn0[kt], an0, 0, 0, 0);
                an1 = __builtin_amdgcn_mfma_f32_16x16x32_f16(ah[kt], wn1[kt], an1, 0, 0, 0);
            }
        } else {
            f32x4 arB0 = {}, arB1 = {};
            #pragma unroll
            for (int kt = 0; kt < 4; ++kt) {
                ar0  = __builtin_amdgcn_mfma_f32_16x16x32_f16(ah[kt],     wh0[kt],     ar0,  0, 0, 0);
                ar1  = __builtin_amdgcn_mfma_f32_16x16x32_f16(ah[kt],     wh1[kt],     ar1,  0, 0, 0);
                arB0 = __builtin_amdgcn_mfma_f32_16x16x32_f16(ah[4 + kt], wh0[4 + kt], arB0, 0, 0, 0);
                arB1 = __builtin_amdgcn_mfma_f32_16x16x32_f16(ah[4 + kt], wh1[4 + kt], arB1, 0, 0, 0);
            }
            ar0 = ar0 + arB0;
            ar1 = ar1 + arB1;
        }

        // emit Zin_next(t-2) in the MFMA shadow
        if constexpr (L < 2) {
            if (k >= 2) {
                uint4 sv;
                sv.x = pk2(anp0[0], anp0[1]); sv.y = pk2(anp0[2], anp0[3]);
                sv.z = pk2(anp1[0], anp1[1]); sv.w = pk2(anp1[2], anp1[3]);
                *(uint4*)(zdst + (size_t)(k - 2) * ZTILE + zoff) = sv;
            }
        }

        float hv[8];
        #pragma unroll
        for (int q = 0; q < 8; ++q) {
            const float S = (q < 4) ? ar0[q] : ar1[q - 4];
            const float e = __builtin_amdgcn_exp2f(S * 2.885390081777927f);
            const float r = __builtin_amdgcn_rcpf(e + 1.f);
            hv[q] = __builtin_fmaf(-2.f, r, 1.f);
        }
        #pragma unroll
        for (int q = 0; q < 8; ++q) {
            const int c = q >> 2, j = q & 3;
            Hb[(cur << 12) + swz(rq * 4 + j, (ct0 + c) * 16 + colw)] = f16bits((_Float16)hv[q]);
        }
        if (L == 2 && cs == NCH - 1 && k == CH - 1) {
            #pragma unroll
            for (int q = 0; q < 8; ++q) {
                const int c = q >> 2, j = q & 3;
                out[(size_t)(grow0 + rq * 4 + j) * 512 + d * 256 + (ct0 + c) * 16 + colw] = hv[q];
            }
        }

        if constexpr (L < 2) { anp0 = an0; anp1 = an1; }
        zc = za; za = zb; zb = zd;

        __builtin_amdgcn_sched_barrier(0);
        asm volatile("s_waitcnt lgkmcnt(0)" ::: "memory");
        __builtin_amdgcn_s_barrier();
        __builtin_amdgcn_sched_barrier(0);
    }

    if constexpr (L < 2) {
        {   // emit slot CH-2
            uint4 sv;
            sv.x = pk2(anp0[0], anp0[1]); sv.y = pk2(anp0[2], anp0[3]);
            sv.z = pk2(anp1[0], anp1[1]); sv.w = pk2(anp1[2], anp1[3]);
            *(uint4*)(zdst + (size_t)(CH - 2) * ZTILE + zoff) = sv;
        }
        // tail: slot CH-1 from final h (buffer 1)
        f32x4 an0 = (f32x4){bn0, bn0, bn0, bn0};
        f32x4 an1 = (f32x4){bn1, bn1, bn1, bn1};
        #pragma unroll
        for (int kt = 0; kt < 8; ++kt) {
            const f16x8 ah = *(const f16x8*)&Hb[(1 << 12) + swz(colw, kt * 32 + rq8)];
            an0 = __builtin_amdgcn_mfma_f32_16x16x32_f16(ah, wn0[kt], an0, 0, 0, 0);
            an1 = __builtin_amdgcn_mfma_f32_16x16x32_f16(ah, wn1[kt], an1, 0, 0, 0);
        }
        uint4 sv;
        sv.x = pk2(an0[0], an0[1]); sv.y = pk2(an0[2], an0[3]);
        sv.z = pk2(an1[0], an1[1]); sv.w = pk2(an1[2], an1[3]);
        *(uint4*)(zdst + (size_t)(CH - 1) * ZTILE + zoff) = sv;
    }
    {   // h carry out (final h in buffer 1; CH even)
        uint16_t* hc = hcarry + (size_t)(d * 3 + L) * 131072;
        const int row = tid >> 5, c8 = (tid & 31) * 8;
        *(uint4*)(hc + (size_t)(grow0 + row) * 256 + c8) =
            *(const uint4*)&Hb[4096 + ((row * 256 + c8) ^ ((row & 7) << 3))];
    }
}

__global__ __attribute__((amdgpu_flat_work_group_size(NT, NT), amdgpu_waves_per_eu(2)))
void rnn_rec(const _Float16* whh_all, const _Float16* wihn_all,
             uint16_t* z0, uint16_t* z1, uint16_t* z2,
             uint16_t* hcarry, const float* fb, const float* bb,
             float* out, int slot)
{
    __shared__ uint16_t Hb[2 * 4096];
    const int l = blockIdx.x >> 6, sub = blockIdx.x & 63;
    const int d = sub >> 5, i = sub & 31;
    const int cs = slot - l;
    if (cs < 0 || cs >= NCH) return;
    const size_t ringE = (size_t)((cs & 1) * 2 + d) * RING_E;
    if (l == 0) {
        const uint16_t* zs = z0 + ((size_t)d * SEQ + (size_t)cs * CH) * ZTILE;
        rec_run<0>(whh_all, wihn_all, zs, z1 + ringE, hcarry, fb, bb, out, d, i, cs, Hb);
    } else if (l == 1) {
        rec_run<1>(whh_all, wihn_all, z1 + ringE, z2 + ringE, hcarry, fb, bb, out, d, i, cs, Hb);
    } else {
        rec_run<2>(whh_all, wihn_all, z2 + ringE, nullptr, hcarry, fb, bb, out, d, i, cs, Hb);
    }
}

extern "C" void kernel_launch(void* const* d_in, const int* in_sizes, int n_in,
                              void* d_out, int out_size, void* d_ws, size_t ws_size,
                              hipStream_t stream)
{
    (void)in_sizes; (void)n_in; (void)out_size; (void)ws_size;
    const float* x      = (const float*)d_in[0];
    const float* fW_ih0 = (const float*)d_in[1];
    const float* fW_ih  = (const float*)d_in[2];
    const float* fW_hh  = (const float*)d_in[3];
    const float* fb     = (const float*)d_in[4];
    const float* bW_ih0 = (const float*)d_in[5];
    const float* bW_ih  = (const float*)d_in[6];
    const float* bW_hh  = (const float*)d_in[7];
    const float* bb     = (const float*)d_in[8];
    uint8_t* ws = (uint8_t*)d_ws;

    _Float16* wf     = (_Float16*)ws;
    uint16_t* hcarry = (uint16_t*)(ws + HC_BYTE);
    uint16_t* z0     = (uint16_t*)(ws + Z0_BYTE);
    uint16_t* z1     = (uint16_t*)(ws + Z1_BYTE);
    uint16_t* z2     = (uint16_t*)(ws + Z2_BYTE);
    const _Float16* whh  = wf + WHH_E;
    const _Float16* wihn = wf + WIHN_E;
    float* out = (float*)d_out;

    rnn_prep<<<400, 256, 0, stream>>>(fW_ih0, fW_ih, fW_hh, bW_ih0, bW_ih, bW_hh, wf);
    rnn_gemm0<<<1024, NT, 0, stream>>>(x, wf, fb, bb, z0);
    for (int s = 0; s < NSLOT; ++s)
        rnn_rec<<<192, NT, 0, stream>>>(whh, wihn, z0, z1, z2, hcarry, fb, bb, out, s);
}